// Round 3
// baseline (1269.696 us; speedup 1.0000x reference)
//
#include <hip/hip_runtime.h>
#include <math.h>

typedef __attribute__((ext_vector_type(8))) short short8v;   // 8 bf16 = 4 VGPR
typedef __attribute__((ext_vector_type(4))) short short4v;
typedef __attribute__((ext_vector_type(4))) float f32x4;

__device__ __forceinline__ short f2bf(float x) {
  unsigned u = __float_as_uint(x);
  u += 0x7fff + ((u >> 16) & 1);          // round-to-nearest-even
  return (short)(u >> 16);
}
__device__ __forceinline__ float bf2f(short s) {
  return __uint_as_float(((unsigned)(unsigned short)s) << 16);
}

// ============ weight prep: W[k][n] fp32 -> Wt_hi/lo[n][k] bf16 (transpose+split) ====
struct WP { const float* src; short* hi; short* lo; };
struct WPArgs { WP w[6]; };

__global__ __launch_bounds__(256)
void wprep_kernel(WPArgs args) {
  __shared__ float tile[32][33];
  const WP wp = args.w[blockIdx.z];
  const int t  = threadIdx.x;
  const int r  = t >> 3;            // 0..31
  const int c  = (t & 7) * 4;       // 0..28
  const int n0 = blockIdx.x * 32;
  const int k0 = blockIdx.y * 32;
  float4 v = *(const float4*)(wp.src + (size_t)(k0 + r) * 1024 + n0 + c);
  tile[r][c] = v.x; tile[r][c + 1] = v.y; tile[r][c + 2] = v.z; tile[r][c + 3] = v.w;
  __syncthreads();
  short4v h, l;
  #pragma unroll
  for (int i = 0; i < 4; ++i) {
    float x = tile[c + i][r];       // transposed: row n=r, col k=k0+c+i
    h[i] = f2bf(x);
    l[i] = f2bf(x - bf2f(h[i]));
  }
  *(short4v*)(wp.hi + (size_t)(n0 + r) * 1024 + k0 + c) = h;
  *(short4v*)(wp.lo + (size_t)(n0 + r) * 1024 + k0 + c) = l;
}

// ============ activation split: fp32[M][1024] -> hi/lo bf16 ============
__global__ __launch_bounds__(256)
void aconv_kernel(const float* __restrict__ in, short* __restrict__ hi,
                  short* __restrict__ lo, int n4) {
  int i = blockIdx.x * 256 + threadIdx.x;
  if (i >= n4) return;
  float4 v = ((const float4*)in)[i];
  short4v h, l;
  h[0] = f2bf(v.x); l[0] = f2bf(v.x - bf2f(h[0]));
  h[1] = f2bf(v.y); l[1] = f2bf(v.y - bf2f(h[1]));
  h[2] = f2bf(v.z); l[2] = f2bf(v.z - bf2f(h[2]));
  h[3] = f2bf(v.w); l[3] = f2bf(v.w - bf2f(h[3]));
  ((short4v*)hi)[i] = h;
  ((short4v*)lo)[i] = l;
}

// ============ split-bf16 MFMA GEMM: C[M,1024] = (Ah+Al) @ (Bh+Bl)^T' + bias =========
// A hi/lo: [M][1024] row-major. B hi/lo: Wt[n][k] (pre-transposed weights).
// MODE 0: write C as hi/lo bf16 split.   MODE 1: Cf = recon(X) + relu(C + bias), fp32.
// Tile 128x128, BK=32, 4 waves (2x2 of 64x64), 16x16x32 bf16 MFMA, 3 products/frag.
template<int MODE>
__global__ __launch_bounds__(256)
void gemm_mfma(const short* __restrict__ Ah, const short* __restrict__ Al,
               const short* __restrict__ Bh, const short* __restrict__ Bl,
               const float* __restrict__ bias,
               const short* __restrict__ Xh, const short* __restrict__ Xl,
               short* __restrict__ Ch, short* __restrict__ Cl,
               float* __restrict__ Cf) {
  __shared__ short sAh[4096], sAl[4096], sBh[4096], sBl[4096];  // [kq][row][8]
  const int t    = threadIdx.x;
  const int bn   = blockIdx.x * 128;
  const int bm   = blockIdx.y * 128;
  const int lane = t & 63;
  const int w    = t >> 6;
  const int wr   = (w >> 1) * 64;       // wave's row base in tile
  const int wc   = (w & 1) * 64;        // wave's col base in tile
  const int lm   = lane & 15;           // frag non-K index
  const int lq   = lane >> 4;           // frag k-chunk / C row-group

  // staging mapping: (row sm, k-chunk kq) ; conflict-free ds_write_b128
  const int sm   = t & 127;
  const int kq0  = t >> 7;              // 0 or 1 (second task: +2)
  const size_t aRow = (size_t)(bm + sm) * 1024;
  const size_t bRow = (size_t)(bn + sm) * 1024;

  f32x4 acc[4][4];
  #pragma unroll
  for (int i = 0; i < 4; ++i)
    #pragma unroll
    for (int j = 0; j < 4; ++j) { f32x4 z = {0.f, 0.f, 0.f, 0.f}; acc[i][j] = z; }

  short8v rAh0, rAh1, rAl0, rAl1, rBh0, rBh1, rBl0, rBl1;
  #define G_LOADS(K0)                                                      \
    rAh0 = *(const short8v*)(Ah + aRow + (K0) + kq0 * 8);                  \
    rAh1 = *(const short8v*)(Ah + aRow + (K0) + (kq0 + 2) * 8);            \
    rAl0 = *(const short8v*)(Al + aRow + (K0) + kq0 * 8);                  \
    rAl1 = *(const short8v*)(Al + aRow + (K0) + (kq0 + 2) * 8);            \
    rBh0 = *(const short8v*)(Bh + bRow + (K0) + kq0 * 8);                  \
    rBh1 = *(const short8v*)(Bh + bRow + (K0) + (kq0 + 2) * 8);            \
    rBl0 = *(const short8v*)(Bl + bRow + (K0) + kq0 * 8);                  \
    rBl1 = *(const short8v*)(Bl + bRow + (K0) + (kq0 + 2) * 8);

  G_LOADS(0)

  for (int k0 = 0; k0 < 1024; k0 += 32) {
    __syncthreads();     // previous iteration's frag reads done
    *(short8v*)&sAh[(kq0 * 128 + sm) * 8]       = rAh0;
    *(short8v*)&sAh[((kq0 + 2) * 128 + sm) * 8] = rAh1;
    *(short8v*)&sAl[(kq0 * 128 + sm) * 8]       = rAl0;
    *(short8v*)&sAl[((kq0 + 2) * 128 + sm) * 8] = rAl1;
    *(short8v*)&sBh[(kq0 * 128 + sm) * 8]       = rBh0;
    *(short8v*)&sBh[((kq0 + 2) * 128 + sm) * 8] = rBh1;
    *(short8v*)&sBl[(kq0 * 128 + sm) * 8]       = rBl0;
    *(short8v*)&sBl[((kq0 + 2) * 128 + sm) * 8] = rBl1;
    __syncthreads();
    if (k0 + 32 < 1024) { G_LOADS(k0 + 32) }   // prefetch next tile under compute

    short8v afh[4], afl[4], bfh[4], bfl[4];
    #pragma unroll
    for (int mi = 0; mi < 4; ++mi) {
      const int arow = wr + mi * 16 + lm;
      afh[mi] = *(const short8v*)&sAh[(lq * 128 + arow) * 8];
      afl[mi] = *(const short8v*)&sAl[(lq * 128 + arow) * 8];
    }
    #pragma unroll
    for (int ni = 0; ni < 4; ++ni) {
      const int bcol = wc + ni * 16 + lm;
      bfh[ni] = *(const short8v*)&sBh[(lq * 128 + bcol) * 8];
      bfl[ni] = *(const short8v*)&sBl[(lq * 128 + bcol) * 8];
    }
    #pragma unroll
    for (int mi = 0; mi < 4; ++mi)
      #pragma unroll
      for (int ni = 0; ni < 4; ++ni) {
        acc[mi][ni] = __builtin_amdgcn_mfma_f32_16x16x32_bf16(afh[mi], bfh[ni], acc[mi][ni], 0, 0, 0);
        acc[mi][ni] = __builtin_amdgcn_mfma_f32_16x16x32_bf16(afh[mi], bfl[ni], acc[mi][ni], 0, 0, 0);
        acc[mi][ni] = __builtin_amdgcn_mfma_f32_16x16x32_bf16(afl[mi], bfh[ni], acc[mi][ni], 0, 0, 0);
      }
  }
  #undef G_LOADS

  float bv[4];
  #pragma unroll
  for (int ni = 0; ni < 4; ++ni) bv[ni] = bias[bn + wc + ni * 16 + lm];

  #pragma unroll
  for (int mi = 0; mi < 4; ++mi)
    #pragma unroll
    for (int ni = 0; ni < 4; ++ni) {
      const int col = bn + wc + ni * 16 + lm;
      #pragma unroll
      for (int j = 0; j < 4; ++j) {
        const int row = bm + wr + mi * 16 + lq * 4 + j;   // verified C/D mapping
        const float v = acc[mi][ni][j] + bv[ni];
        const size_t idx = (size_t)row * 1024 + col;
        if (MODE == 0) {
          short h = f2bf(v);
          Ch[idx] = h;
          Cl[idx] = f2bf(v - bf2f(h));
        } else {
          const float xv = bf2f(Xh[idx]) + bf2f(Xl[idx]);
          Cf[idx] = xv + fmaxf(v, 0.f);
        }
      }
    }
}

// ============ Attention (fp32 VALU; inputs reconstructed from hi/lo) ============
// softmax over q axis: each k-column normalized over all 512 q -> column-local.
#define KS 16
__global__ __launch_bounds__(512)
void attn_kernel(const short* __restrict__ Qh, const short* __restrict__ Ql,
                 const short* __restrict__ K1h, const short* __restrict__ K1l,
                 const short* __restrict__ K2h, const short* __restrict__ K2l,
                 const short* __restrict__ V1h, const short* __restrict__ V1l,
                 const short* __restrict__ V2h, const short* __restrict__ V2l,
                 float* __restrict__ Opart) {
  __shared__ float Ks[KS][64];
  __shared__ float Vs[KS][64];
  __shared__ float P[KS][512];
  __shared__ float invZ[KS];

  const int t  = threadIdx.x;          // q row 0..511
  const int hb = blockIdx.x;           // h*8 + b
  const int kt = blockIdx.y;           // 0: K1/V1, 1: K2/V2
  const int h  = hb >> 3;
  const int b  = hb & 7;
  const short* __restrict__ Ksh = kt ? K2h : K1h;
  const short* __restrict__ Ksl = kt ? K2l : K1l;
  const short* __restrict__ Vsh = kt ? V2h : V1h;
  const short* __restrict__ Vsl = kt ? V2l : V1l;

  float q[64];
  {
    const size_t qo = (size_t)(b * 512 + t) * 1024 + h * 64;
    #pragma unroll
    for (int i = 0; i < 16; ++i) {
      short4v hv = *(const short4v*)(Qh + qo + i * 4);
      short4v lv = *(const short4v*)(Ql + qo + i * 4);
      q[i * 4]     = bf2f(hv[0]) + bf2f(lv[0]);
      q[i * 4 + 1] = bf2f(hv[1]) + bf2f(lv[1]);
      q[i * 4 + 2] = bf2f(hv[2]) + bf2f(lv[2]);
      q[i * 4 + 3] = bf2f(hv[3]) + bf2f(lv[3]);
    }
  }
  float o[64];
  #pragma unroll
  for (int i = 0; i < 64; ++i) o[i] = 0.f;

  const int su   = t & 255;
  const int tile = t >> 8;             // 0: K staging, 1: V staging
  const int sr   = su >> 4;            // 0..15
  const int sc   = (su & 15) * 4;      // 0..60

  for (int ks = 0; ks < 1024 / KS; ++ks) {
    const int kbase = ks * KS;
    __syncthreads();
    {
      const size_t gro = (size_t)(b * 1024 + kbase + sr) * 1024 + h * 64 + sc;
      const short* hs = tile ? Vsh : Ksh;
      const short* ls = tile ? Vsl : Ksl;
      short4v hv = *(const short4v*)(hs + gro);
      short4v lv = *(const short4v*)(ls + gro);
      float4 f = make_float4(bf2f(hv[0]) + bf2f(lv[0]), bf2f(hv[1]) + bf2f(lv[1]),
                             bf2f(hv[2]) + bf2f(lv[2]), bf2f(hv[3]) + bf2f(lv[3]));
      if (tile == 0) *(float4*)&Ks[sr][sc] = f;
      else           *(float4*)&Vs[sr][sc] = f;
    }
    __syncthreads();

    float p[KS];
    #pragma unroll
    for (int r = 0; r < KS; ++r) {
      float s = 0.f;
      #pragma unroll
      for (int j = 0; j < 64; j += 4) {
        float4 kv = *(const float4*)&Ks[r][j];
        s = fmaf(q[j], kv.x, s);     s = fmaf(q[j + 1], kv.y, s);
        s = fmaf(q[j + 2], kv.z, s); s = fmaf(q[j + 3], kv.w, s);
      }
      p[r] = expf(s * 0.03125f);     // scores std ~0.08: exp w/o max-sub is safe
      P[r][t] = p[r];
    }
    __syncthreads();

    {
      const int r   = t >> 5;
      const int seg = t & 31;
      float z = 0.f;
      #pragma unroll
      for (int i = 0; i < 512 / 32; ++i) z += P[r][seg + 32 * i];
      #pragma unroll
      for (int m = 1; m < 32; m <<= 1) z += __shfl_xor(z, m);
      if (seg == 0) invZ[r] = 1.0f / z;
    }
    __syncthreads();

    #pragma unroll
    for (int r = 0; r < KS; ++r) {
      float a = p[r] * invZ[r];
      #pragma unroll
      for (int j = 0; j < 64; j += 4) {
        float4 vv = *(const float4*)&Vs[r][j];
        o[j]     = fmaf(a, vv.x, o[j]);     o[j + 1] = fmaf(a, vv.y, o[j + 1]);
        o[j + 2] = fmaf(a, vv.z, o[j + 2]); o[j + 3] = fmaf(a, vv.w, o[j + 3]);
      }
    }
  }

  float* orow = Opart + (size_t)((kt * 128 + hb) * 512 + t) * 64;
  #pragma unroll
  for (int i = 0; i < 16; ++i)
    *(float4*)&orow[i * 4] = make_float4(o[i * 4], o[i * 4 + 1], o[i * 4 + 2], o[i * 4 + 3]);
}

// ============ LayerNorm ============
// MODE 0: v = recon(Qp) + Op[0] + Op[1] (merge-heads+residual); out = hi/lo split
// MODE 1: v = fin[row]; out = fp32
template<int MODE>
__global__ __launch_bounds__(256)
void ln_kernel(const float* __restrict__ fin, const short* __restrict__ Qph,
               const short* __restrict__ Qpl,
               const float* __restrict__ g, const float* __restrict__ beta,
               short* __restrict__ oh, short* __restrict__ ol,
               float* __restrict__ of) {
  const int row = blockIdx.x;          // b*512 + n
  const int t = threadIdx.x;
  const int c = t * 4;
  float4 v;
  if (MODE == 0) {
    const int b  = row >> 9;
    const int n  = row & 511;
    const int hh = c >> 6;
    const int d  = c & 63;
    const int hb = hh * 8 + b;
    const size_t qi = (size_t)row * 1024 + c;
    short4v qh = *(const short4v*)(Qph + qi);
    short4v ql = *(const short4v*)(Qpl + qi);
    float4 p0 = *(const float4*)&fin[((size_t)hb         * 512 + n) * 64 + d];
    float4 p1 = *(const float4*)&fin[((size_t)(128 + hb) * 512 + n) * 64 + d];
    v = make_float4(bf2f(qh[0]) + bf2f(ql[0]) + p0.x + p1.x,
                    bf2f(qh[1]) + bf2f(ql[1]) + p0.y + p1.y,
                    bf2f(qh[2]) + bf2f(ql[2]) + p0.z + p1.z,
                    bf2f(qh[3]) + bf2f(ql[3]) + p0.w + p1.w);
  } else {
    v = *(const float4*)&fin[(size_t)row * 1024 + c];
  }
  float s  = v.x + v.y + v.z + v.w;
  float s2 = v.x * v.x + v.y * v.y + v.z * v.z + v.w * v.w;
  #pragma unroll
  for (int m = 1; m < 64; m <<= 1) { s += __shfl_xor(s, m); s2 += __shfl_xor(s2, m); }
  __shared__ float aS[4], aS2[4];
  const int wid = t >> 6;
  if ((t & 63) == 0) { aS[wid] = s; aS2[wid] = s2; }
  __syncthreads();
  s  = aS[0] + aS[1] + aS[2] + aS[3];
  s2 = aS2[0] + aS2[1] + aS2[2] + aS2[3];
  const float mean = s * (1.f / 1024.f);
  const float var  = s2 * (1.f / 1024.f) - mean * mean;
  const float rstd = rsqrtf(var + 1e-5f);
  float4 gg = *(const float4*)&g[c];
  float4 bb = *(const float4*)&beta[c];
  float4 ov = make_float4((v.x - mean) * rstd * gg.x + bb.x,
                          (v.y - mean) * rstd * gg.y + bb.y,
                          (v.z - mean) * rstd * gg.z + bb.z,
                          (v.w - mean) * rstd * gg.w + bb.w);
  const size_t oi = (size_t)row * 1024 + c;
  if (MODE == 0) {
    short4v hv, lv;
    hv[0] = f2bf(ov.x); lv[0] = f2bf(ov.x - bf2f(hv[0]));
    hv[1] = f2bf(ov.y); lv[1] = f2bf(ov.y - bf2f(hv[1]));
    hv[2] = f2bf(ov.z); lv[2] = f2bf(ov.z - bf2f(hv[2]));
    hv[3] = f2bf(ov.w); lv[3] = f2bf(ov.w - bf2f(hv[3]));
    *(short4v*)(oh + oi) = hv;
    *(short4v*)(ol + oi) = lv;
  } else {
    *(float4*)(of + oi) = ov;
  }
}

extern "C" void kernel_launch(void* const* d_in, const int* in_sizes, int n_in,
                              void* d_out, int out_size, void* d_ws, size_t ws_size,
                              hipStream_t stream) {
  (void)in_sizes; (void)n_in; (void)out_size; (void)ws_size;
  const float* Q   = (const float*)d_in[0];
  const float* K1  = (const float*)d_in[1];
  const float* K2  = (const float*)d_in[2];
  const float* Wq  = (const float*)d_in[3];
  const float* bq  = (const float*)d_in[4];
  const float* Wk1 = (const float*)d_in[5];
  const float* bk1 = (const float*)d_in[6];
  const float* Wk2 = (const float*)d_in[7];
  const float* bk2 = (const float*)d_in[8];
  const float* Wv1 = (const float*)d_in[9];
  const float* bv1 = (const float*)d_in[10];
  const float* Wv2 = (const float*)d_in[11];
  const float* bv2 = (const float*)d_in[12];
  const float* Wo  = (const float*)d_in[13];
  const float* bo  = (const float*)d_in[14];
  const float* g0  = (const float*)d_in[15];
  const float* be0 = (const float*)d_in[16];
  const float* g1  = (const float*)d_in[17];
  const float* be1 = (const float*)d_in[18];

  // ---- workspace layout (byte offsets; total 248 MB) ----
  // [0,16M)    Qc hi/lo          -> reused as x0 hi/lo after GEMM1 dead
  // [16M,48M)  K1c hi/lo         -> [16M,32M) reused as tb (fp32) after GEMM2 dead
  // [48M,80M)  K2c hi/lo         -> reused as Op (fp32, 32MB) after GEMM3 dead
  // [80M,104M) Wt hi/lo x6 (2MB each pair-half)
  // [104M,120M) Qp hi/lo ; [120M,152M) K1p ; [152M,184M) K2p ;
  // [184M,216M) V1p ; [216M,248M) V2p
  char* WS = (char*)d_ws;
  const size_t MB = 1024 * 1024;
  auto S = [&](size_t off) { return (short*)(WS + off); };
  short *Qch = S(0),        *Qcl = S(8 * MB);
  short *K1ch = S(16 * MB), *K1cl = S(32 * MB);
  short *K2ch = S(48 * MB), *K2cl = S(64 * MB);
  short *Wth[6], *Wtl[6];
  for (int i = 0; i < 6; ++i) { Wth[i] = S(80 * MB + i * 4 * MB); Wtl[i] = S(80 * MB + i * 4 * MB + 2 * MB); }
  short *Qph = S(104 * MB),  *Qpl = S(112 * MB);
  short *K1ph = S(120 * MB), *K1pl = S(136 * MB);
  short *K2ph = S(152 * MB), *K2pl = S(168 * MB);
  short *V1ph = S(184 * MB), *V1pl = S(200 * MB);
  short *V2ph = S(216 * MB), *V2pl = S(232 * MB);
  float* Op  = (float*)(WS + 48 * MB);   // overlays K2c (dead after GEMM3)
  short *x0h = S(0), *x0l = S(8 * MB);   // overlays Qc (dead after GEMM1)
  float* tb  = (float*)(WS + 16 * MB);   // overlays K1ch (dead after GEMM2)

  WPArgs wa;
  const float* wsrc[6] = {Wq, Wk1, Wk2, Wv1, Wv2, Wo};
  for (int i = 0; i < 6; ++i) { wa.w[i].src = wsrc[i]; wa.w[i].hi = Wth[i]; wa.w[i].lo = Wtl[i]; }

  wprep_kernel<<<dim3(32, 32, 6), 256, 0, stream>>>(wa);
  aconv_kernel<<<dim3(4096), 256, 0, stream>>>(Q,  Qch,  Qcl,  1048576);
  aconv_kernel<<<dim3(8192), 256, 0, stream>>>(K1, K1ch, K1cl, 2097152);
  aconv_kernel<<<dim3(8192), 256, 0, stream>>>(K2, K2ch, K2cl, 2097152);

  gemm_mfma<0><<<dim3(8, 32), 256, 0, stream>>>(Qch,  Qcl,  Wth[0], Wtl[0], bq,  nullptr, nullptr, Qph,  Qpl,  nullptr);
  gemm_mfma<0><<<dim3(8, 64), 256, 0, stream>>>(K1ch, K1cl, Wth[1], Wtl[1], bk1, nullptr, nullptr, K1ph, K1pl, nullptr);
  gemm_mfma<0><<<dim3(8, 64), 256, 0, stream>>>(K2ch, K2cl, Wth[2], Wtl[2], bk2, nullptr, nullptr, K2ph, K2pl, nullptr);
  gemm_mfma<0><<<dim3(8, 64), 256, 0, stream>>>(K1ph, K1pl, Wth[3], Wtl[3], bv1, nullptr, nullptr, V1ph, V1pl, nullptr);
  gemm_mfma<0><<<dim3(8, 64), 256, 0, stream>>>(K2ph, K2pl, Wth[4], Wtl[4], bv2, nullptr, nullptr, V2ph, V2pl, nullptr);

  attn_kernel<<<dim3(128, 2), dim3(512), 0, stream>>>(Qph, Qpl, K1ph, K1pl, K2ph, K2pl,
                                                      V1ph, V1pl, V2ph, V2pl, Op);

  ln_kernel<0><<<dim3(4096), 256, 0, stream>>>(Op, Qph, Qpl, g0, be0, x0h, x0l, nullptr);
  gemm_mfma<1><<<dim3(8, 32), 256, 0, stream>>>(x0h, x0l, Wth[5], Wtl[5], bo, x0h, x0l, nullptr, nullptr, tb);
  ln_kernel<1><<<dim3(4096), 256, 0, stream>>>(tb, nullptr, nullptr, g1, be1, nullptr, nullptr, (float*)d_out);
}

// Round 4
// 1050.123 us; speedup vs baseline: 1.2091x; 1.2091x over previous
//
#include <hip/hip_runtime.h>
#include <math.h>

typedef __attribute__((ext_vector_type(8))) short short8v;   // 8 bf16 = 4 VGPR
typedef __attribute__((ext_vector_type(4))) short short4v;
typedef __attribute__((ext_vector_type(4))) float f32x4;

__device__ __forceinline__ short f2bf(float x) {
  unsigned u = __float_as_uint(x);
  u += 0x7fff + ((u >> 16) & 1);          // round-to-nearest-even
  return (short)(u >> 16);
}
__device__ __forceinline__ float bf2f(short s) {
  return __uint_as_float(((unsigned)(unsigned short)s) << 16);
}

// ============ weight prep: W[k][n] fp32 -> Wt_hi/lo[n][k] bf16 (transpose+split) ====
struct WP { const float* src; short* hi; short* lo; };
struct WPArgs { WP w[6]; };

__global__ __launch_bounds__(256)
void wprep_kernel(WPArgs args) {
  __shared__ float tile[32][33];
  const WP wp = args.w[blockIdx.z];
  const int t  = threadIdx.x;
  const int r  = t >> 3;            // 0..31
  const int c  = (t & 7) * 4;       // 0..28
  const int n0 = blockIdx.x * 32;
  const int k0 = blockIdx.y * 32;
  float4 v = *(const float4*)(wp.src + (size_t)(k0 + r) * 1024 + n0 + c);
  tile[r][c] = v.x; tile[r][c + 1] = v.y; tile[r][c + 2] = v.z; tile[r][c + 3] = v.w;
  __syncthreads();
  short4v h, l;
  #pragma unroll
  for (int i = 0; i < 4; ++i) {
    float x = tile[c + i][r];       // transposed: row n=r, col k=k0+c+i
    h[i] = f2bf(x);
    l[i] = f2bf(x - bf2f(h[i]));
  }
  *(short4v*)(wp.hi + (size_t)(n0 + r) * 1024 + k0 + c) = h;
  *(short4v*)(wp.lo + (size_t)(n0 + r) * 1024 + k0 + c) = l;
}

// ============ activation split: fp32[M][1024] -> hi/lo bf16 ============
__global__ __launch_bounds__(256)
void aconv_kernel(const float* __restrict__ in, short* __restrict__ hi,
                  short* __restrict__ lo, int n4) {
  int i = blockIdx.x * 256 + threadIdx.x;
  if (i >= n4) return;
  float4 v = ((const float4*)in)[i];
  short4v h, l;
  h[0] = f2bf(v.x); l[0] = f2bf(v.x - bf2f(h[0]));
  h[1] = f2bf(v.y); l[1] = f2bf(v.y - bf2f(h[1]));
  h[2] = f2bf(v.z); l[2] = f2bf(v.z - bf2f(h[2]));
  h[3] = f2bf(v.w); l[3] = f2bf(v.w - bf2f(h[3]));
  ((short4v*)hi)[i] = h;
  ((short4v*)lo)[i] = l;
}

// ============ split-bf16 MFMA GEMM ============
// MODE 0: write C as hi/lo bf16 split.
// MODE 1: Cf = recon(X) + relu(C + bias), fp32.
// MODE 2: write C TRANSPOSED as single bf16: Vt[n][row] (row-stride 8192).
template<int MODE>
__global__ __launch_bounds__(256)
void gemm_mfma(const short* __restrict__ Ah, const short* __restrict__ Al,
               const short* __restrict__ Bh, const short* __restrict__ Bl,
               const float* __restrict__ bias,
               const short* __restrict__ Xh, const short* __restrict__ Xl,
               short* __restrict__ Ch, short* __restrict__ Cl,
               float* __restrict__ Cf, short* __restrict__ Vt) {
  __shared__ short sAh[4096], sAl[4096], sBh[4096], sBl[4096];  // [kq][row][8]
  const int t    = threadIdx.x;
  const int bn   = blockIdx.x * 128;
  const int bm   = blockIdx.y * 128;
  const int lane = t & 63;
  const int w    = t >> 6;
  const int wr   = (w >> 1) * 64;
  const int wc   = (w & 1) * 64;
  const int lm   = lane & 15;
  const int lq   = lane >> 4;

  const int sm   = t & 127;
  const int kq0  = t >> 7;              // 0 or 1 (second task: +2)
  const size_t aRow = (size_t)(bm + sm) * 1024;
  const size_t bRow = (size_t)(bn + sm) * 1024;

  f32x4 acc[4][4];
  #pragma unroll
  for (int i = 0; i < 4; ++i)
    #pragma unroll
    for (int j = 0; j < 4; ++j) { f32x4 z = {0.f, 0.f, 0.f, 0.f}; acc[i][j] = z; }

  short8v rAh0, rAh1, rAl0, rAl1, rBh0, rBh1, rBl0, rBl1;
  #define G_LOADS(K0)                                                      \
    rAh0 = *(const short8v*)(Ah + aRow + (K0) + kq0 * 8);                  \
    rAh1 = *(const short8v*)(Ah + aRow + (K0) + (kq0 + 2) * 8);            \
    rAl0 = *(const short8v*)(Al + aRow + (K0) + kq0 * 8);                  \
    rAl1 = *(const short8v*)(Al + aRow + (K0) + (kq0 + 2) * 8);            \
    rBh0 = *(const short8v*)(Bh + bRow + (K0) + kq0 * 8);                  \
    rBh1 = *(const short8v*)(Bh + bRow + (K0) + (kq0 + 2) * 8);            \
    rBl0 = *(const short8v*)(Bl + bRow + (K0) + kq0 * 8);                  \
    rBl1 = *(const short8v*)(Bl + bRow + (K0) + (kq0 + 2) * 8);

  G_LOADS(0)

  for (int k0 = 0; k0 < 1024; k0 += 32) {
    __syncthreads();
    *(short8v*)&sAh[(kq0 * 128 + sm) * 8]       = rAh0;
    *(short8v*)&sAh[((kq0 + 2) * 128 + sm) * 8] = rAh1;
    *(short8v*)&sAl[(kq0 * 128 + sm) * 8]       = rAl0;
    *(short8v*)&sAl[((kq0 + 2) * 128 + sm) * 8] = rAl1;
    *(short8v*)&sBh[(kq0 * 128 + sm) * 8]       = rBh0;
    *(short8v*)&sBh[((kq0 + 2) * 128 + sm) * 8] = rBh1;
    *(short8v*)&sBl[(kq0 * 128 + sm) * 8]       = rBl0;
    *(short8v*)&sBl[((kq0 + 2) * 128 + sm) * 8] = rBl1;
    __syncthreads();
    if (k0 + 32 < 1024) { G_LOADS(k0 + 32) }

    short8v afh[4], afl[4], bfh[4], bfl[4];
    #pragma unroll
    for (int mi = 0; mi < 4; ++mi) {
      const int arow = wr + mi * 16 + lm;
      afh[mi] = *(const short8v*)&sAh[(lq * 128 + arow) * 8];
      afl[mi] = *(const short8v*)&sAl[(lq * 128 + arow) * 8];
    }
    #pragma unroll
    for (int ni = 0; ni < 4; ++ni) {
      const int bcol = wc + ni * 16 + lm;
      bfh[ni] = *(const short8v*)&sBh[(lq * 128 + bcol) * 8];
      bfl[ni] = *(const short8v*)&sBl[(lq * 128 + bcol) * 8];
    }
    #pragma unroll
    for (int mi = 0; mi < 4; ++mi)
      #pragma unroll
      for (int ni = 0; ni < 4; ++ni) {
        acc[mi][ni] = __builtin_amdgcn_mfma_f32_16x16x32_bf16(afh[mi], bfh[ni], acc[mi][ni], 0, 0, 0);
        acc[mi][ni] = __builtin_amdgcn_mfma_f32_16x16x32_bf16(afh[mi], bfl[ni], acc[mi][ni], 0, 0, 0);
        acc[mi][ni] = __builtin_amdgcn_mfma_f32_16x16x32_bf16(afl[mi], bfh[ni], acc[mi][ni], 0, 0, 0);
      }
  }
  #undef G_LOADS

  float bv[4];
  #pragma unroll
  for (int ni = 0; ni < 4; ++ni) bv[ni] = bias[bn + wc + ni * 16 + lm];

  #pragma unroll
  for (int mi = 0; mi < 4; ++mi)
    #pragma unroll
    for (int ni = 0; ni < 4; ++ni) {
      const int col = bn + wc + ni * 16 + lm;
      if (MODE == 2) {
        const int row0 = bm + wr + mi * 16 + lq * 4;
        short4v pv;
        #pragma unroll
        for (int j = 0; j < 4; ++j) pv[j] = f2bf(acc[mi][ni][j] + bv[ni]);
        *(short4v*)(Vt + (size_t)col * 8192 + row0) = pv;
      } else {
        #pragma unroll
        for (int j = 0; j < 4; ++j) {
          const int row = bm + wr + mi * 16 + lq * 4 + j;
          const float v = acc[mi][ni][j] + bv[ni];
          const size_t idx = (size_t)row * 1024 + col;
          if (MODE == 0) {
            short hh = f2bf(v);
            Ch[idx] = hh;
            Cl[idx] = f2bf(v - bf2f(hh));
          } else {
            const float xv = bf2f(Xh[idx]) + bf2f(Xl[idx]);
            Cf[idx] = xv + fmaxf(v, 0.f);
          }
        }
      }
    }
}

// ============ MFMA attention ============
// Block = (hb, ks): head-batch hb = h*8+b, ks selects K1/V1 (0) or K2/V2 (1).
// All 512 q in-block (softmax is over q -> column-local Z). 8 waves, wave w owns
// q-range [w*64, w*64+64). 16 k-tiles of 64. S via 3-term split MFMA; P bf16 via
// swizzled LDS; V pre-scaled by invZ (folds softmax divide); PV 1-term MFMA.
__global__ __launch_bounds__(512, 2)
void attn_mfma(const short* __restrict__ Qph, const short* __restrict__ Qpl,
               const short* __restrict__ K1h, const short* __restrict__ K1l,
               const short* __restrict__ K2h, const short* __restrict__ K2l,
               const short* __restrict__ VT1, const short* __restrict__ VT2,
               float* __restrict__ Opart) {
  __shared__ short sKh[4096];       // [dc][k][8]  8KB
  __shared__ short sKl[4096];       // 8KB
  __shared__ short sV[4096];        // [kc][d][8]  8KB (invZ-scaled V', bf16)
  __shared__ short sP[32768];       // [q][k] swizzled, 64KB
  __shared__ float sZ[8][64];       // per-wave column partials
  __shared__ float sInvZ[64];

  const int t    = threadIdx.x;
  const int lane = t & 63;
  const int w    = t >> 6;          // wave 0..7
  const int lm   = lane & 15;
  const int lq   = lane >> 4;
  const int hb   = blockIdx.x;
  const int ks   = blockIdx.y;
  const int h    = hb >> 3;
  const int b    = hb & 7;
  const int qw   = w * 64;
  const short* __restrict__ Kh = ks ? K2h : K1h;
  const short* __restrict__ Kl = ks ? K2l : K1l;
  const short* __restrict__ VT = ks ? VT2 : VT1;

  // Q fragments held in registers for the whole kernel: [mi][dh]
  short8v qh[4][2], ql[4][2];
  #pragma unroll
  for (int mi = 0; mi < 4; ++mi)
    #pragma unroll
    for (int dh = 0; dh < 2; ++dh) {
      const size_t qa = (size_t)(b * 512 + qw + mi * 16 + lm) * 1024 + h * 64 + dh * 32 + lq * 8;
      qh[mi][dh] = *(const short8v*)(Qph + qa);
      ql[mi][dh] = *(const short8v*)(Qpl + qa);
    }

  f32x4 o[4][4];
  #pragma unroll
  for (int i = 0; i < 4; ++i)
    #pragma unroll
    for (int j = 0; j < 4; ++j) { f32x4 z = {0.f, 0.f, 0.f, 0.f}; o[i][j] = z; }

  const int sd = t & 63;            // staging row (K: k ; V: d)
  const int sc = t >> 6;            // staging chunk 0..7
  char* sPb = (char*)sP;

  for (int kt = 0; kt < 16; ++kt) {
    const int k0 = kt * 64;

    // ---- stage K tile (hi/lo). sK not read by PV phase, so no barrier needed
    // before the write: reaching here implies all waves passed bar4(kt-1),
    // hence all S-phase reads of sK(kt-1) are done.
    {
      const size_t g = (size_t)(b * 1024 + k0 + sd) * 1024 + h * 64 + sc * 8;
      short8v vh = *(const short8v*)(Kh + g);
      short8v vl = *(const short8v*)(Kl + g);
      *(short8v*)&sKh[(sc * 64 + sd) * 8] = vh;
      *(short8v*)&sKl[(sc * 64 + sd) * 8] = vl;
    }
    __syncthreads();   // bar1: sK ready; also orders PV(kt-1) before sP writes below

    // ---- S = Q.K^T (3-term split), exp, column partials, P-write
    f32x4 s[4][4];
    #pragma unroll
    for (int i = 0; i < 4; ++i)
      #pragma unroll
      for (int j = 0; j < 4; ++j) { f32x4 z = {0.f, 0.f, 0.f, 0.f}; s[i][j] = z; }

    #pragma unroll
    for (int dh = 0; dh < 2; ++dh) {
      short8v kbh[4], kbl[4];
      #pragma unroll
      for (int fi = 0; fi < 4; ++fi) {
        const int addr = ((dh * 4 + lq) * 64 + fi * 16 + lm) * 8;
        kbh[fi] = *(const short8v*)&sKh[addr];
        kbl[fi] = *(const short8v*)&sKl[addr];
      }
      #pragma unroll
      for (int mi = 0; mi < 4; ++mi)
        #pragma unroll
        for (int fi = 0; fi < 4; ++fi) {
          s[mi][fi] = __builtin_amdgcn_mfma_f32_16x16x32_bf16(qh[mi][dh], kbh[fi], s[mi][fi], 0, 0, 0);
          s[mi][fi] = __builtin_amdgcn_mfma_f32_16x16x32_bf16(qh[mi][dh], kbl[fi], s[mi][fi], 0, 0, 0);
          s[mi][fi] = __builtin_amdgcn_mfma_f32_16x16x32_bf16(ql[mi][dh], kbh[fi], s[mi][fi], 0, 0, 0);
        }
    }

    float zp[4] = {0.f, 0.f, 0.f, 0.f};
    #pragma unroll
    for (int mi = 0; mi < 4; ++mi)
      #pragma unroll
      for (int fi = 0; fi < 4; ++fi)
        #pragma unroll
        for (int j = 0; j < 4; ++j) {
          float p = expf(s[mi][fi][j] * 0.03125f);   // scores small: no max-sub needed
          s[mi][fi][j] = p;
          zp[fi] += p;
        }
    #pragma unroll
    for (int fi = 0; fi < 4; ++fi) {
      float z = zp[fi];
      z += __shfl_xor(z, 16);
      z += __shfl_xor(z, 32);
      if (lane < 16) sZ[w][fi * 16 + lm] = z;
    }
    // P -> LDS (bf16), chunk-XOR swizzle: byte(q,k) = q*128 + ((k>>3)^(q&7))*16 + (k&7)*2
    #pragma unroll
    for (int mi = 0; mi < 4; ++mi) {
      const int qb = qw + mi * 16 + lq * 4;
      #pragma unroll
      for (int fi = 0; fi < 4; ++fi) {
        const int k = fi * 16 + lm;
        #pragma unroll
        for (int j = 0; j < 4; ++j) {
          const int q = qb + j;
          *(short*)(sPb + q * 128 + ((((k >> 3) ^ (q & 7))) << 4) + ((k & 7) << 1)) =
              f2bf(s[mi][fi][j]);
        }
      }
    }
    __syncthreads();   // bar2: sZ + sP complete

    // ---- invZ (threads 0..63) ; VT tile load (all threads, latency overlapped)
    if (t < 64) {
      float z = 0.f;
      #pragma unroll
      for (int wv = 0; wv < 8; ++wv) z += sZ[wv][t];
      sInvZ[t] = 1.0f / z;
    }
    short8v vreg = *(const short8v*)(VT + (size_t)(h * 64 + sd) * 8192 + b * 1024 + k0 + sc * 8);
    __syncthreads();   // bar3: sInvZ ready

    {
      short8v vs;
      #pragma unroll
      for (int i = 0; i < 8; ++i) vs[i] = f2bf(bf2f(vreg[i]) * sInvZ[sc * 8 + i]);
      *(short8v*)&sV[(sc * 64 + sd) * 8] = vs;
    }
    __syncthreads();   // bar4: sV ready

    // ---- PV: O += P . V'
    #pragma unroll
    for (int kh = 0; kh < 2; ++kh) {
      short8v vb[4], pa[4];
      #pragma unroll
      for (int ni = 0; ni < 4; ++ni)
        vb[ni] = *(const short8v*)&sV[((kh * 4 + lq) * 64 + ni * 16 + lm) * 8];
      #pragma unroll
      for (int mi = 0; mi < 4; ++mi) {
        const int q = qw + mi * 16 + lm;
        pa[mi] = *(const short8v*)(sPb + q * 128 + (((kh * 4 + lq) ^ (q & 7)) << 4));
      }
      #pragma unroll
      for (int mi = 0; mi < 4; ++mi)
        #pragma unroll
        for (int ni = 0; ni < 4; ++ni)
          o[mi][ni] = __builtin_amdgcn_mfma_f32_16x16x32_bf16(pa[mi], vb[ni], o[mi][ni], 0, 0, 0);
    }
  }

  // ---- epilogue: Opart[ks][hb][q][d]
  float* dst = Opart + (size_t)(ks * 128 + hb) * 512 * 64;
  #pragma unroll
  for (int mi = 0; mi < 4; ++mi)
    #pragma unroll
    for (int ni = 0; ni < 4; ++ni)
      #pragma unroll
      for (int j = 0; j < 4; ++j) {
        const int q = qw + mi * 16 + lq * 4 + j;
        const int d = ni * 16 + lm;
        dst[(size_t)q * 64 + d] = o[mi][ni][j];
      }
}

// ============ LayerNorm ============
// MODE 0: v = recon(Qp) + Op[0] + Op[1] (merge-heads+residual); out = hi/lo split
// MODE 1: v = fin[row]; out = fp32
template<int MODE>
__global__ __launch_bounds__(256)
void ln_kernel(const float* __restrict__ fin, const short* __restrict__ Qph,
               const short* __restrict__ Qpl,
               const float* __restrict__ g, const float* __restrict__ beta,
               short* __restrict__ oh, short* __restrict__ ol,
               float* __restrict__ of) {
  const int row = blockIdx.x;          // b*512 + n
  const int t = threadIdx.x;
  const int c = t * 4;
  float4 v;
  if (MODE == 0) {
    const int b  = row >> 9;
    const int n  = row & 511;
    const int hh = c >> 6;
    const int d  = c & 63;
    const int hb = hh * 8 + b;
    const size_t qi = (size_t)row * 1024 + c;
    short4v qh = *(const short4v*)(Qph + qi);
    short4v ql = *(const short4v*)(Qpl + qi);
    float4 p0 = *(const float4*)&fin[((size_t)hb         * 512 + n) * 64 + d];
    float4 p1 = *(const float4*)&fin[((size_t)(128 + hb) * 512 + n) * 64 + d];
    v = make_float4(bf2f(qh[0]) + bf2f(ql[0]) + p0.x + p1.x,
                    bf2f(qh[1]) + bf2f(ql[1]) + p0.y + p1.y,
                    bf2f(qh[2]) + bf2f(ql[2]) + p0.z + p1.z,
                    bf2f(qh[3]) + bf2f(ql[3]) + p0.w + p1.w);
  } else {
    v = *(const float4*)&fin[(size_t)row * 1024 + c];
  }
  float s  = v.x + v.y + v.z + v.w;
  float s2 = v.x * v.x + v.y * v.y + v.z * v.z + v.w * v.w;
  #pragma unroll
  for (int m = 1; m < 64; m <<= 1) { s += __shfl_xor(s, m); s2 += __shfl_xor(s2, m); }
  __shared__ float aS[4], aS2[4];
  const int wid = t >> 6;
  if ((t & 63) == 0) { aS[wid] = s; aS2[wid] = s2; }
  __syncthreads();
  s  = aS[0] + aS[1] + aS[2] + aS[3];
  s2 = aS2[0] + aS2[1] + aS2[2] + aS2[3];
  const float mean = s * (1.f / 1024.f);
  const float var  = s2 * (1.f / 1024.f) - mean * mean;
  const float rstd = rsqrtf(var + 1e-5f);
  float4 gg = *(const float4*)&g[c];
  float4 bb = *(const float4*)&beta[c];
  float4 ov = make_float4((v.x - mean) * rstd * gg.x + bb.x,
                          (v.y - mean) * rstd * gg.y + bb.y,
                          (v.z - mean) * rstd * gg.z + bb.z,
                          (v.w - mean) * rstd * gg.w + bb.w);
  const size_t oi = (size_t)row * 1024 + c;
  if (MODE == 0) {
    short4v hv, lv;
    hv[0] = f2bf(ov.x); lv[0] = f2bf(ov.x - bf2f(hv[0]));
    hv[1] = f2bf(ov.y); lv[1] = f2bf(ov.y - bf2f(hv[1]));
    hv[2] = f2bf(ov.z); lv[2] = f2bf(ov.z - bf2f(hv[2]));
    hv[3] = f2bf(ov.w); lv[3] = f2bf(ov.w - bf2f(hv[3]));
    *(short4v*)(oh + oi) = hv;
    *(short4v*)(ol + oi) = lv;
  } else {
    *(float4*)(of + oi) = ov;
  }
}

extern "C" void kernel_launch(void* const* d_in, const int* in_sizes, int n_in,
                              void* d_out, int out_size, void* d_ws, size_t ws_size,
                              hipStream_t stream) {
  (void)in_sizes; (void)n_in; (void)out_size; (void)ws_size;
  const float* Q   = (const float*)d_in[0];
  const float* K1  = (const float*)d_in[1];
  const float* K2  = (const float*)d_in[2];
  const float* Wq  = (const float*)d_in[3];
  const float* bq  = (const float*)d_in[4];
  const float* Wk1 = (const float*)d_in[5];
  const float* bk1 = (const float*)d_in[6];
  const float* Wk2 = (const float*)d_in[7];
  const float* bk2 = (const float*)d_in[8];
  const float* Wv1 = (const float*)d_in[9];
  const float* bv1 = (const float*)d_in[10];
  const float* Wv2 = (const float*)d_in[11];
  const float* bv2 = (const float*)d_in[12];
  const float* Wo  = (const float*)d_in[13];
  const float* bo  = (const float*)d_in[14];
  const float* g0  = (const float*)d_in[15];
  const float* be0 = (const float*)d_in[16];
  const float* g1  = (const float*)d_in[17];
  const float* be1 = (const float*)d_in[18];

  // ---- workspace layout (byte offsets; total 216 MB) ----
  // [0,16M)    Qc hi/lo          -> reused as x0 hi/lo after GEMM1 dead
  // [16M,48M)  K1c hi/lo         -> [16M,32M) reused as tb (fp32) after GEMM2 dead
  // [48M,80M)  K2c hi/lo         -> reused as Opart (fp32, 32MB) after GEMM3 dead
  // [80M,104M) Wt hi/lo x6
  // [104M,120M) Qp hi/lo ; [120M,152M) K1p hi/lo ; [152M,184M) K2p hi/lo
  // [184M,200M) VT1 bf16 [1024][8192] ; [200M,216M) VT2
  char* WS = (char*)d_ws;
  const size_t MB = 1024 * 1024;
  auto S = [&](size_t off) { return (short*)(WS + off); };
  short *Qch = S(0),        *Qcl = S(8 * MB);
  short *K1ch = S(16 * MB), *K1cl = S(32 * MB);
  short *K2ch = S(48 * MB), *K2cl = S(64 * MB);
  short *Wth[6], *Wtl[6];
  for (int i = 0; i < 6; ++i) { Wth[i] = S(80 * MB + i * 4 * MB); Wtl[i] = S(80 * MB + i * 4 * MB + 2 * MB); }
  short *Qph = S(104 * MB),  *Qpl = S(112 * MB);
  short *K1ph = S(120 * MB), *K1pl = S(136 * MB);
  short *K2ph = S(152 * MB), *K2pl = S(168 * MB);
  short *VT1 = S(184 * MB),  *VT2 = S(200 * MB);
  float* Op  = (float*)(WS + 48 * MB);   // overlays K2c (dead after K2-projection)
  short *x0h = S(0), *x0l = S(8 * MB);   // overlays Qc (dead after Q-projection)
  float* tb  = (float*)(WS + 16 * MB);   // overlays K1ch (dead after K1-projection)

  WPArgs wa;
  const float* wsrc[6] = {Wq, Wk1, Wk2, Wv1, Wv2, Wo};
  for (int i = 0; i < 6; ++i) { wa.w[i].src = wsrc[i]; wa.w[i].hi = Wth[i]; wa.w[i].lo = Wtl[i]; }

  wprep_kernel<<<dim3(32, 32, 6), 256, 0, stream>>>(wa);
  aconv_kernel<<<dim3(4096), 256, 0, stream>>>(Q,  Qch,  Qcl,  1048576);
  aconv_kernel<<<dim3(8192), 256, 0, stream>>>(K1, K1ch, K1cl, 2097152);
  aconv_kernel<<<dim3(8192), 256, 0, stream>>>(K2, K2ch, K2cl, 2097152);

  gemm_mfma<0><<<dim3(8, 32), 256, 0, stream>>>(Qch,  Qcl,  Wth[0], Wtl[0], bq,  nullptr, nullptr, Qph,  Qpl,  nullptr, nullptr);
  gemm_mfma<0><<<dim3(8, 64), 256, 0, stream>>>(K1ch, K1cl, Wth[1], Wtl[1], bk1, nullptr, nullptr, K1ph, K1pl, nullptr, nullptr);
  gemm_mfma<0><<<dim3(8, 64), 256, 0, stream>>>(K2ch, K2cl, Wth[2], Wtl[2], bk2, nullptr, nullptr, K2ph, K2pl, nullptr, nullptr);
  gemm_mfma<2><<<dim3(8, 64), 256, 0, stream>>>(K1ph, K1pl, Wth[3], Wtl[3], bv1, nullptr, nullptr, nullptr, nullptr, nullptr, VT1);
  gemm_mfma<2><<<dim3(8, 64), 256, 0, stream>>>(K2ph, K2pl, Wth[4], Wtl[4], bv2, nullptr, nullptr, nullptr, nullptr, nullptr, VT2);

  attn_mfma<<<dim3(128, 2), dim3(512), 0, stream>>>(Qph, Qpl, K1ph, K1pl, K2ph, K2pl,
                                                    VT1, VT2, Op);

  ln_kernel<0><<<dim3(4096), 256, 0, stream>>>(Op, Qph, Qpl, g0, be0, x0h, x0l, nullptr);
  gemm_mfma<1><<<dim3(8, 32), 256, 0, stream>>>(x0h, x0l, Wth[5], Wtl[5], bo, x0h, x0l, nullptr, nullptr, tb, nullptr);
  ln_kernel<1><<<dim3(4096), 256, 0, stream>>>(tb, nullptr, nullptr, g1, be1, nullptr, nullptr, (float*)d_out);
}

// Round 5
// 689.110 us; speedup vs baseline: 1.8425x; 1.5239x over previous
//
#include <hip/hip_runtime.h>
#include <math.h>

typedef __attribute__((ext_vector_type(8))) short short8v;   // 8 bf16 = 4 VGPR
typedef __attribute__((ext_vector_type(4))) short short4v;
typedef __attribute__((ext_vector_type(4))) float f32x4;

__device__ __forceinline__ short f2bf(float x) {
  unsigned u = __float_as_uint(x);
  u += 0x7fff + ((u >> 16) & 1);          // round-to-nearest-even
  return (short)(u >> 16);
}
__device__ __forceinline__ float bf2f(short s) {
  return __uint_as_float(((unsigned)(unsigned short)s) << 16);
}

// ============ weight prep: W[k][n] fp32 -> Wt_hi/lo[n][k] bf16 (transpose+split) ====
struct WP { const float* src; short* hi; short* lo; };
struct WPArgs { WP w[6]; };

__global__ __launch_bounds__(256)
void wprep_kernel(WPArgs args) {
  __shared__ float tile[32][33];
  const WP wp = args.w[blockIdx.z];
  const int t  = threadIdx.x;
  const int r  = t >> 3;            // 0..31
  const int c  = (t & 7) * 4;       // 0..28
  const int n0 = blockIdx.x * 32;
  const int k0 = blockIdx.y * 32;
  float4 v = *(const float4*)(wp.src + (size_t)(k0 + r) * 1024 + n0 + c);
  tile[r][c] = v.x; tile[r][c + 1] = v.y; tile[r][c + 2] = v.z; tile[r][c + 3] = v.w;
  __syncthreads();
  short4v h, l;
  #pragma unroll
  for (int i = 0; i < 4; ++i) {
    float x = tile[c + i][r];       // transposed: row n=r, col k=k0+c+i
    h[i] = f2bf(x);
    l[i] = f2bf(x - bf2f(h[i]));
  }
  *(short4v*)(wp.hi + (size_t)(n0 + r) * 1024 + k0 + c) = h;
  *(short4v*)(wp.lo + (size_t)(n0 + r) * 1024 + k0 + c) = l;
}

// ============ activation split: fp32[M][1024] -> hi/lo bf16 ============
__global__ __launch_bounds__(256)
void aconv_kernel(const float* __restrict__ in, short* __restrict__ hi,
                  short* __restrict__ lo, int n4) {
  int i = blockIdx.x * 256 + threadIdx.x;
  if (i >= n4) return;
  float4 v = ((const float4*)in)[i];
  short4v h, l;
  h[0] = f2bf(v.x); l[0] = f2bf(v.x - bf2f(h[0]));
  h[1] = f2bf(v.y); l[1] = f2bf(v.y - bf2f(h[1]));
  h[2] = f2bf(v.z); l[2] = f2bf(v.z - bf2f(h[2]));
  h[3] = f2bf(v.w); l[3] = f2bf(v.w - bf2f(h[3]));
  ((short4v*)hi)[i] = h;
  ((short4v*)lo)[i] = l;
}

// ============ split-bf16 MFMA GEMM ============
// MODE 0: write C as hi/lo bf16 split.
// MODE 1: Cf = recon(X) + relu(C + bias), fp32.
// MODE 2: write C TRANSPOSED as single bf16: Vt[n][row] (row-stride 8192).
template<int MODE>
__global__ __launch_bounds__(256)
void gemm_mfma(const short* __restrict__ Ah, const short* __restrict__ Al,
               const short* __restrict__ Bh, const short* __restrict__ Bl,
               const float* __restrict__ bias,
               const short* __restrict__ Xh, const short* __restrict__ Xl,
               short* __restrict__ Ch, short* __restrict__ Cl,
               float* __restrict__ Cf, short* __restrict__ Vt) {
  __shared__ short sAh[4096], sAl[4096], sBh[4096], sBl[4096];  // [kq][row][8]
  const int t    = threadIdx.x;
  const int bn   = blockIdx.x * 128;
  const int bm   = blockIdx.y * 128;
  const int lane = t & 63;
  const int w    = t >> 6;
  const int wr   = (w >> 1) * 64;
  const int wc   = (w & 1) * 64;
  const int lm   = lane & 15;
  const int lq   = lane >> 4;

  const int sm   = t & 127;
  const int kq0  = t >> 7;              // 0 or 1 (second task: +2)
  const size_t aRow = (size_t)(bm + sm) * 1024;
  const size_t bRow = (size_t)(bn + sm) * 1024;

  f32x4 acc[4][4];
  #pragma unroll
  for (int i = 0; i < 4; ++i)
    #pragma unroll
    for (int j = 0; j < 4; ++j) { f32x4 z = {0.f, 0.f, 0.f, 0.f}; acc[i][j] = z; }

  short8v rAh0, rAh1, rAl0, rAl1, rBh0, rBh1, rBl0, rBl1;
  #define G_LOADS(K0)                                                      \
    rAh0 = *(const short8v*)(Ah + aRow + (K0) + kq0 * 8);                  \
    rAh1 = *(const short8v*)(Ah + aRow + (K0) + (kq0 + 2) * 8);            \
    rAl0 = *(const short8v*)(Al + aRow + (K0) + kq0 * 8);                  \
    rAl1 = *(const short8v*)(Al + aRow + (K0) + (kq0 + 2) * 8);            \
    rBh0 = *(const short8v*)(Bh + bRow + (K0) + kq0 * 8);                  \
    rBh1 = *(const short8v*)(Bh + bRow + (K0) + (kq0 + 2) * 8);            \
    rBl0 = *(const short8v*)(Bl + bRow + (K0) + kq0 * 8);                  \
    rBl1 = *(const short8v*)(Bl + bRow + (K0) + (kq0 + 2) * 8);

  G_LOADS(0)

  for (int k0 = 0; k0 < 1024; k0 += 32) {
    __syncthreads();
    *(short8v*)&sAh[(kq0 * 128 + sm) * 8]       = rAh0;
    *(short8v*)&sAh[((kq0 + 2) * 128 + sm) * 8] = rAh1;
    *(short8v*)&sAl[(kq0 * 128 + sm) * 8]       = rAl0;
    *(short8v*)&sAl[((kq0 + 2) * 128 + sm) * 8] = rAl1;
    *(short8v*)&sBh[(kq0 * 128 + sm) * 8]       = rBh0;
    *(short8v*)&sBh[((kq0 + 2) * 128 + sm) * 8] = rBh1;
    *(short8v*)&sBl[(kq0 * 128 + sm) * 8]       = rBl0;
    *(short8v*)&sBl[((kq0 + 2) * 128 + sm) * 8] = rBl1;
    __syncthreads();
    if (k0 + 32 < 1024) { G_LOADS(k0 + 32) }

    short8v afh[4], afl[4], bfh[4], bfl[4];
    #pragma unroll
    for (int mi = 0; mi < 4; ++mi) {
      const int arow = wr + mi * 16 + lm;
      afh[mi] = *(const short8v*)&sAh[(lq * 128 + arow) * 8];
      afl[mi] = *(const short8v*)&sAl[(lq * 128 + arow) * 8];
    }
    #pragma unroll
    for (int ni = 0; ni < 4; ++ni) {
      const int bcol = wc + ni * 16 + lm;
      bfh[ni] = *(const short8v*)&sBh[(lq * 128 + bcol) * 8];
      bfl[ni] = *(const short8v*)&sBl[(lq * 128 + bcol) * 8];
    }
    #pragma unroll
    for (int mi = 0; mi < 4; ++mi)
      #pragma unroll
      for (int ni = 0; ni < 4; ++ni) {
        acc[mi][ni] = __builtin_amdgcn_mfma_f32_16x16x32_bf16(afh[mi], bfh[ni], acc[mi][ni], 0, 0, 0);
        acc[mi][ni] = __builtin_amdgcn_mfma_f32_16x16x32_bf16(afh[mi], bfl[ni], acc[mi][ni], 0, 0, 0);
        acc[mi][ni] = __builtin_amdgcn_mfma_f32_16x16x32_bf16(afl[mi], bfh[ni], acc[mi][ni], 0, 0, 0);
      }
  }
  #undef G_LOADS

  float bv[4];
  #pragma unroll
  for (int ni = 0; ni < 4; ++ni) bv[ni] = bias[bn + wc + ni * 16 + lm];

  #pragma unroll
  for (int mi = 0; mi < 4; ++mi)
    #pragma unroll
    for (int ni = 0; ni < 4; ++ni) {
      const int col = bn + wc + ni * 16 + lm;
      if (MODE == 2) {
        const int row0 = bm + wr + mi * 16 + lq * 4;
        short4v pv;
        #pragma unroll
        for (int j = 0; j < 4; ++j) pv[j] = f2bf(acc[mi][ni][j] + bv[ni]);
        *(short4v*)(Vt + (size_t)col * 8192 + row0) = pv;
      } else {
        #pragma unroll
        for (int j = 0; j < 4; ++j) {
          const int row = bm + wr + mi * 16 + lq * 4 + j;
          const float v = acc[mi][ni][j] + bv[ni];
          const size_t idx = (size_t)row * 1024 + col;
          if (MODE == 0) {
            short hh = f2bf(v);
            Ch[idx] = hh;
            Cl[idx] = f2bf(v - bf2f(hh));
          } else {
            const float xv = bf2f(Xh[idx]) + bf2f(Xl[idx]);
            Cf[idx] = xv + fmaxf(v, 0.f);
          }
        }
      }
    }
}

// ============ MFMA attention v3 ============
// Grid (hb=128, ks=2). Block = 1024 threads = 16 waves; wave w owns q-range
// [w*32, w*32+32). 32 k-tiles of KVBLK=32. Softmax over q => Z[k] block-local.
// Per tile: stage K(hi/lo)+V via reg-prefetch into double-buffered LDS (2 bars),
// S via 3-term split MFMA, Z via shfl + cross-wave LDS, P scaled by invZ and
// written bf16 to per-wave LDS scratch (intra-wave, no barrier), PV 1-term MFMA.
__global__ __launch_bounds__(1024, 4)
void attn_mfma(const short* __restrict__ Qph, const short* __restrict__ Qpl,
               const short* __restrict__ K1h, const short* __restrict__ K1l,
               const short* __restrict__ K2h, const short* __restrict__ K2l,
               const short* __restrict__ VT1, const short* __restrict__ VT2,
               float* __restrict__ Opart) {
  __shared__ short sK[2][2][2048];     // [buf][hi/lo][dchunk 8][k 32][8]  16KB
  __shared__ short sV[2][2560];        // [buf][d 64][k 32 pad->40]        10KB
  __shared__ short sP[20480];          // per-wave [q 32][k 32 pad->40]    40KB
  __shared__ float sZ[16][32];         // per-wave column partials          2KB

  const int t    = threadIdx.x;
  const int lane = t & 63;
  const int w    = t >> 6;             // wave 0..15
  const int lm   = lane & 15;
  const int lq   = lane >> 4;
  const int hb   = blockIdx.x;
  const int ks   = blockIdx.y;
  const int h    = hb >> 3;
  const int b    = hb & 7;
  const int qw   = w * 32;
  const short* __restrict__ Kh = ks ? K2h : K1h;
  const short* __restrict__ Kl = ks ? K2l : K1l;
  const short* __restrict__ VT = ks ? VT2 : VT1;

  // Q fragments in registers for the whole kernel: [mi 0..1][dh 0..1]
  short8v qh[2][2], ql[2][2];
  #pragma unroll
  for (int mi = 0; mi < 2; ++mi)
    #pragma unroll
    for (int dh = 0; dh < 2; ++dh) {
      const size_t qa = (size_t)(b * 512 + qw + mi * 16 + lm) * 1024 + h * 64 + dh * 32 + lq * 8;
      qh[mi][dh] = *(const short8v*)(Qph + qa);
      ql[mi][dh] = *(const short8v*)(Qpl + qa);
    }

  f32x4 o[2][4];
  #pragma unroll
  for (int i = 0; i < 2; ++i)
    #pragma unroll
    for (int j = 0; j < 4; ++j) { f32x4 z = {0.f, 0.f, 0.f, 0.f}; o[i][j] = z; }

  // staging roles: t<256 K-hi, t<512 K-lo, t<768 V, rest idle (still compute)
  const int ku = t & 255;
  const int sd = ku & 31;              // k row
  const int sc = ku >> 5;              // d chunk 0..7
  const int vd = ku & 63;              // V d row
  const int vc = (ku >> 6) & 3;        // V k chunk 0..3
  short* sPw = sP + w * 1280;          // per-wave 32x40 shorts

  short8v rk, rv;
  #define ISSUE_LOADS(K0)                                                            \
    if (t < 512) {                                                                   \
      const short* __restrict__ src = (t < 256) ? Kh : Kl;                           \
      rk = *(const short8v*)(src + (size_t)(b * 1024 + (K0) + sd) * 1024 + h * 64 + sc * 8); \
    } else if (t < 768) {                                                            \
      rv = *(const short8v*)(VT + (size_t)(h * 64 + vd) * 8192 + b * 1024 + (K0) + vc * 8);  \
    }

  ISSUE_LOADS(0)

  for (int kt = 0; kt < 32; ++kt) {
    const int c = kt & 1;
    // ---- stage regs -> LDS buf[c] (vmcnt wait auto-inserted by data dep)
    if (t < 512)      *(short8v*)&sK[c][t < 256 ? 0 : 1][(sc * 32 + sd) * 8] = rk;
    else if (t < 768) *(short8v*)&sV[c][vd * 40 + vc * 8] = rv;
    if (kt + 1 < 32) { ISSUE_LOADS((kt + 1) * 32) }
    __syncthreads();   // barB: buf[c] ready (buf[c] last read finished before
                       // barC of kt-1 -> safe to have written it above)

    // ---- S = Q.K^T (3-term split)
    f32x4 s[2][2];
    #pragma unroll
    for (int i = 0; i < 2; ++i)
      #pragma unroll
      for (int j = 0; j < 2; ++j) { f32x4 z = {0.f, 0.f, 0.f, 0.f}; s[i][j] = z; }

    #pragma unroll
    for (int dh = 0; dh < 2; ++dh) {
      short8v kbh[2], kbl[2];
      #pragma unroll
      for (int fi = 0; fi < 2; ++fi) {
        const int addr = ((dh * 4 + lq) * 32 + fi * 16 + lm) * 8;
        kbh[fi] = *(const short8v*)&sK[c][0][addr];
        kbl[fi] = *(const short8v*)&sK[c][1][addr];
      }
      #pragma unroll
      for (int mi = 0; mi < 2; ++mi)
        #pragma unroll
        for (int fi = 0; fi < 2; ++fi) {
          s[mi][fi] = __builtin_amdgcn_mfma_f32_16x16x32_bf16(qh[mi][dh], kbh[fi], s[mi][fi], 0, 0, 0);
          s[mi][fi] = __builtin_amdgcn_mfma_f32_16x16x32_bf16(qh[mi][dh], kbl[fi], s[mi][fi], 0, 0, 0);
          s[mi][fi] = __builtin_amdgcn_mfma_f32_16x16x32_bf16(ql[mi][dh], kbh[fi], s[mi][fi], 0, 0, 0);
        }
    }

    // ---- exp + per-wave column partials (k = fi*16+lm, q over mi,lq,j)
    float zp[2] = {0.f, 0.f};
    #pragma unroll
    for (int mi = 0; mi < 2; ++mi)
      #pragma unroll
      for (int fi = 0; fi < 2; ++fi)
        #pragma unroll
        for (int j = 0; j < 4; ++j) {
          float p = __expf(s[mi][fi][j] * 0.03125f);   // scores tiny: no max-sub
          s[mi][fi][j] = p;
          zp[fi] += p;
        }
    #pragma unroll
    for (int fi = 0; fi < 2; ++fi) {
      zp[fi] += __shfl_xor(zp[fi], 16);
      zp[fi] += __shfl_xor(zp[fi], 32);
    }
    if (lane < 16) { sZ[w][lm] = zp[0]; sZ[w][16 + lm] = zp[1]; }
    __syncthreads();   // barC: sZ complete

    // ---- invZ: lanes<32 each own one k column, then shfl-distribute
    float iz = 0.f;
    if (lane < 32) {
      float z = 0.f;
      #pragma unroll
      for (int wv = 0; wv < 16; ++wv) z += sZ[wv][lane];
      iz = 1.0f / z;
    }
    const float iz0 = __shfl(iz, lm);
    const float iz1 = __shfl(iz, 16 + lm);

    // ---- P*invZ -> per-wave LDS (bf16); intra-wave only, no barrier needed
    #pragma unroll
    for (int mi = 0; mi < 2; ++mi)
      #pragma unroll
      for (int j = 0; j < 4; ++j) {
        const int q = mi * 16 + lq * 4 + j;
        sPw[q * 40 + lm]      = f2bf(s[mi][0][j] * iz0);
        sPw[q * 40 + 16 + lm] = f2bf(s[mi][1][j] * iz1);
      }

    // ---- PV: O += P . V  (K-dim = 32 = one MFMA)
    short8v pa[2], vb[4];
    #pragma unroll
    for (int mi = 0; mi < 2; ++mi)
      pa[mi] = *(const short8v*)&sPw[(mi * 16 + lm) * 40 + lq * 8];
    #pragma unroll
    for (int ni = 0; ni < 4; ++ni)
      vb[ni] = *(const short8v*)&sV[c][(ni * 16 + lm) * 40 + lq * 8];
    #pragma unroll
    for (int mi = 0; mi < 2; ++mi)
      #pragma unroll
      for (int ni = 0; ni < 4; ++ni)
        o[mi][ni] = __builtin_amdgcn_mfma_f32_16x16x32_bf16(pa[mi], vb[ni], o[mi][ni], 0, 0, 0);
  }
  #undef ISSUE_LOADS

  // ---- epilogue: Opart[ks][hb][q][d]
  float* dst = Opart + (size_t)(ks * 128 + hb) * 512 * 64;
  #pragma unroll
  for (int mi = 0; mi < 2; ++mi)
    #pragma unroll
    for (int ni = 0; ni < 4; ++ni)
      #pragma unroll
      for (int j = 0; j < 4; ++j) {
        const int q = qw + mi * 16 + lq * 4 + j;
        const int d = ni * 16 + lm;
        dst[(size_t)q * 64 + d] = o[mi][ni][j];
      }
}

// ============ LayerNorm ============
// MODE 0: v = recon(Qp) + Op[0] + Op[1] (merge-heads+residual); out = hi/lo split
// MODE 1: v = fin[row]; out = fp32
template<int MODE>
__global__ __launch_bounds__(256)
void ln_kernel(const float* __restrict__ fin, const short* __restrict__ Qph,
               const short* __restrict__ Qpl,
               const float* __restrict__ g, const float* __restrict__ beta,
               short* __restrict__ oh, short* __restrict__ ol,
               float* __restrict__ of) {
  const int row = blockIdx.x;          // b*512 + n
  const int t = threadIdx.x;
  const int c = t * 4;
  float4 v;
  if (MODE == 0) {
    const int b  = row >> 9;
    const int n  = row & 511;
    const int hh = c >> 6;
    const int d  = c & 63;
    const int hb = hh * 8 + b;
    const size_t qi = (size_t)row * 1024 + c;
    short4v qh = *(const short4v*)(Qph + qi);
    short4v ql = *(const short4v*)(Qpl + qi);
    float4 p0 = *(const float4*)&fin[((size_t)hb         * 512 + n) * 64 + d];
    float4 p1 = *(const float4*)&fin[((size_t)(128 + hb) * 512 + n) * 64 + d];
    v = make_float4(bf2f(qh[0]) + bf2f(ql[0]) + p0.x + p1.x,
                    bf2f(qh[1]) + bf2f(ql[1]) + p0.y + p1.y,
                    bf2f(qh[2]) + bf2f(ql[2]) + p0.z + p1.z,
                    bf2f(qh[3]) + bf2f(ql[3]) + p0.w + p1.w);
  } else {
    v = *(const float4*)&fin[(size_t)row * 1024 + c];
  }
  float s  = v.x + v.y + v.z + v.w;
  float s2 = v.x * v.x + v.y * v.y + v.z * v.z + v.w * v.w;
  #pragma unroll
  for (int m = 1; m < 64; m <<= 1) { s += __shfl_xor(s, m); s2 += __shfl_xor(s2, m); }
  __shared__ float aS[4], aS2[4];
  const int wid = t >> 6;
  if ((t & 63) == 0) { aS[wid] = s; aS2[wid] = s2; }
  __syncthreads();
  s  = aS[0] + aS[1] + aS[2] + aS[3];
  s2 = aS2[0] + aS2[1] + aS2[2] + aS2[3];
  const float mean = s * (1.f / 1024.f);
  const float var  = s2 * (1.f / 1024.f) - mean * mean;
  const float rstd = rsqrtf(var + 1e-5f);
  float4 gg = *(const float4*)&g[c];
  float4 bb = *(const float4*)&beta[c];
  float4 ov = make_float4((v.x - mean) * rstd * gg.x + bb.x,
                          (v.y - mean) * rstd * gg.y + bb.y,
                          (v.z - mean) * rstd * gg.z + bb.z,
                          (v.w - mean) * rstd * gg.w + bb.w);
  const size_t oi = (size_t)row * 1024 + c;
  if (MODE == 0) {
    short4v hv, lv;
    hv[0] = f2bf(ov.x); lv[0] = f2bf(ov.x - bf2f(hv[0]));
    hv[1] = f2bf(ov.y); lv[1] = f2bf(ov.y - bf2f(hv[1]));
    hv[2] = f2bf(ov.z); lv[2] = f2bf(ov.z - bf2f(hv[2]));
    hv[3] = f2bf(ov.w); lv[3] = f2bf(ov.w - bf2f(hv[3]));
    *(short4v*)(oh + oi) = hv;
    *(short4v*)(ol + oi) = lv;
  } else {
    *(float4*)(of + oi) = ov;
  }
}

extern "C" void kernel_launch(void* const* d_in, const int* in_sizes, int n_in,
                              void* d_out, int out_size, void* d_ws, size_t ws_size,
                              hipStream_t stream) {
  (void)in_sizes; (void)n_in; (void)out_size; (void)ws_size;
  const float* Q   = (const float*)d_in[0];
  const float* K1  = (const float*)d_in[1];
  const float* K2  = (const float*)d_in[2];
  const float* Wq  = (const float*)d_in[3];
  const float* bq  = (const float*)d_in[4];
  const float* Wk1 = (const float*)d_in[5];
  const float* bk1 = (const float*)d_in[6];
  const float* Wk2 = (const float*)d_in[7];
  const float* bk2 = (const float*)d_in[8];
  const float* Wv1 = (const float*)d_in[9];
  const float* bv1 = (const float*)d_in[10];
  const float* Wv2 = (const float*)d_in[11];
  const float* bv2 = (const float*)d_in[12];
  const float* Wo  = (const float*)d_in[13];
  const float* bo  = (const float*)d_in[14];
  const float* g0  = (const float*)d_in[15];
  const float* be0 = (const float*)d_in[16];
  const float* g1  = (const float*)d_in[17];
  const float* be1 = (const float*)d_in[18];

  // ---- workspace layout (byte offsets; total 216 MB) ----
  char* WS = (char*)d_ws;
  const size_t MB = 1024 * 1024;
  auto S = [&](size_t off) { return (short*)(WS + off); };
  short *Qch = S(0),        *Qcl = S(8 * MB);
  short *K1ch = S(16 * MB), *K1cl = S(32 * MB);
  short *K2ch = S(48 * MB), *K2cl = S(64 * MB);
  short *Wth[6], *Wtl[6];
  for (int i = 0; i < 6; ++i) { Wth[i] = S(80 * MB + i * 4 * MB); Wtl[i] = S(80 * MB + i * 4 * MB + 2 * MB); }
  short *Qph = S(104 * MB),  *Qpl = S(112 * MB);
  short *K1ph = S(120 * MB), *K1pl = S(136 * MB);
  short *K2ph = S(152 * MB), *K2pl = S(168 * MB);
  short *VT1 = S(184 * MB),  *VT2 = S(200 * MB);
  float* Op  = (float*)(WS + 48 * MB);   // overlays K2c (dead after K2-projection)
  short *x0h = S(0), *x0l = S(8 * MB);   // overlays Qc (dead after Q-projection)
  float* tb  = (float*)(WS + 16 * MB);   // overlays K1ch (dead after K1-projection)

  WPArgs wa;
  const float* wsrc[6] = {Wq, Wk1, Wk2, Wv1, Wv2, Wo};
  for (int i = 0; i < 6; ++i) { wa.w[i].src = wsrc[i]; wa.w[i].hi = Wth[i]; wa.w[i].lo = Wtl[i]; }

  wprep_kernel<<<dim3(32, 32, 6), 256, 0, stream>>>(wa);
  aconv_kernel<<<dim3(4096), 256, 0, stream>>>(Q,  Qch,  Qcl,  1048576);
  aconv_kernel<<<dim3(8192), 256, 0, stream>>>(K1, K1ch, K1cl, 2097152);
  aconv_kernel<<<dim3(8192), 256, 0, stream>>>(K2, K2ch, K2cl, 2097152);

  gemm_mfma<0><<<dim3(8, 32), 256, 0, stream>>>(Qch,  Qcl,  Wth[0], Wtl[0], bq,  nullptr, nullptr, Qph,  Qpl,  nullptr, nullptr);
  gemm_mfma<0><<<dim3(8, 64), 256, 0, stream>>>(K1ch, K1cl, Wth[1], Wtl[1], bk1, nullptr, nullptr, K1ph, K1pl, nullptr, nullptr);
  gemm_mfma<0><<<dim3(8, 64), 256, 0, stream>>>(K2ch, K2cl, Wth[2], Wtl[2], bk2, nullptr, nullptr, K2ph, K2pl, nullptr, nullptr);
  gemm_mfma<2><<<dim3(8, 64), 256, 0, stream>>>(K1ph, K1pl, Wth[3], Wtl[3], bv1, nullptr, nullptr, nullptr, nullptr, nullptr, VT1);
  gemm_mfma<2><<<dim3(8, 64), 256, 0, stream>>>(K2ph, K2pl, Wth[4], Wtl[4], bv2, nullptr, nullptr, nullptr, nullptr, nullptr, VT2);

  attn_mfma<<<dim3(128, 2), dim3(1024), 0, stream>>>(Qph, Qpl, K1ph, K1pl, K2ph, K2pl,
                                                     VT1, VT2, Op);

  ln_kernel<0><<<dim3(4096), 256, 0, stream>>>(Op, Qph, Qpl, g0, be0, x0h, x0l, nullptr);
  gemm_mfma<1><<<dim3(8, 32), 256, 0, stream>>>(x0h, x0l, Wth[5], Wtl[5], bo, x0h, x0l, nullptr, nullptr, tb, nullptr);
  ln_kernel<1><<<dim3(4096), 256, 0, stream>>>(tb, nullptr, nullptr, g1, be1, nullptr, nullptr, (float*)d_out);
}

// Round 6
// 492.549 us; speedup vs baseline: 2.5778x; 1.3991x over previous
//
#include <hip/hip_runtime.h>
#include <math.h>

typedef __attribute__((ext_vector_type(8))) _Float16 half8v;   // 8 fp16 = 4 VGPR
typedef __attribute__((ext_vector_type(4))) _Float16 half4v;
typedef __attribute__((ext_vector_type(4))) float f32x4;

__device__ __forceinline__ void gload16(const void* g, void* l) {
  // global -> LDS direct DMA, 16 B per lane. LDS dest must be wave-uniform
  // base + lane*16 (verified for every call site below).
  __builtin_amdgcn_global_load_lds(
      (const __attribute__((address_space(1))) void*)g,
      (__attribute__((address_space(3))) void*)l, 16, 0, 0);
}

// ============ weight prep: W[k][n] fp32 -> Wt[n][k] fp16 (transpose+cast) ============
struct WP { const float* src; _Float16* dst; };
struct WPArgs { WP w[6]; };

__global__ __launch_bounds__(256)
void wprep_kernel(WPArgs args) {
  __shared__ float tile[32][33];
  const WP wp = args.w[blockIdx.z];
  const int t  = threadIdx.x;
  const int r  = t >> 3;            // 0..31
  const int c  = (t & 7) * 4;       // 0..28
  const int n0 = blockIdx.x * 32;
  const int k0 = blockIdx.y * 32;
  float4 v = *(const float4*)(wp.src + (size_t)(k0 + r) * 1024 + n0 + c);
  tile[r][c] = v.x; tile[r][c + 1] = v.y; tile[r][c + 2] = v.z; tile[r][c + 3] = v.w;
  __syncthreads();
  half4v h;
  #pragma unroll
  for (int i = 0; i < 4; ++i) h[i] = (_Float16)tile[c + i][r];
  *(half4v*)(wp.dst + (size_t)(n0 + r) * 1024 + k0 + c) = h;
}

// ============ activation cast: fp32 -> fp16 ============
__global__ __launch_bounds__(256)
void aconv_kernel(const float* __restrict__ in, _Float16* __restrict__ out, int n4) {
  int i = blockIdx.x * 256 + threadIdx.x;
  if (i >= n4) return;
  float4 v = ((const float4*)in)[i];
  half4v o;
  o[0] = (_Float16)v.x; o[1] = (_Float16)v.y; o[2] = (_Float16)v.z; o[3] = (_Float16)v.w;
  ((half4v*)out)[i] = o;
}

// ============ fp16 MFMA GEMM: C[M,1024] = A @ Wt^T + bias ============
// A[M][1024] fp16 row-major; B = Wt[n][k] fp16 (pre-transposed weights).
// 128x128 tile, BK=64, 4 waves (2x2 of 64x64), global_load_lds staging, 2-phase.
// MODE 0: C fp16.  MODE 1: Cf = X + relu(C+bias) fp32.  MODE 2: C^T fp16 Vt[n][8192].
template<int MODE>
__global__ __launch_bounds__(256)
void gemm_fp16(const _Float16* __restrict__ A, const _Float16* __restrict__ B,
               const float* __restrict__ bias, const _Float16* __restrict__ X,
               _Float16* __restrict__ C, float* __restrict__ Cf,
               _Float16* __restrict__ Vt) {
  __shared__ _Float16 sA[8192];   // [kq 0..7][row 0..127][8]  16KB
  __shared__ _Float16 sB[8192];   // 16KB
  const int t    = threadIdx.x;
  const int bn   = blockIdx.x * 128;
  const int bm   = blockIdx.y * 128;
  const int lane = t & 63;
  const int w    = t >> 6;
  const int wr   = (w >> 1) * 64;
  const int wc   = (w & 1) * 64;
  const int lm   = lane & 15;
  const int lq   = lane >> 4;

  f32x4 acc[4][4];
  #pragma unroll
  for (int i = 0; i < 4; ++i)
    #pragma unroll
    for (int j = 0; j < 4; ++j) { f32x4 z = {0.f, 0.f, 0.f, 0.f}; acc[i][j] = z; }

  for (int k0 = 0; k0 < 1024; k0 += 64) {
    __syncthreads();                     // frag reads of previous iter complete
    #pragma unroll
    for (int i = 0; i < 4; ++i) {
      const int T    = w * 4 + i;        // 0..15: kq = T>>1, row-half = T&1
      const int kq   = T >> 1;
      const int row  = (T & 1) * 64 + lane;
      // LDS byte addr = T*1024 + lane*16 : wave-uniform base + lane*16  ✓
      gload16(A + (size_t)(bm + row) * 1024 + k0 + kq * 8, &sA[(T * 64 + lane) * 8]);
      gload16(B + (size_t)(bn + row) * 1024 + k0 + kq * 8, &sB[(T * 64 + lane) * 8]);
    }
    __syncthreads();                     // compiler drains vmcnt(0) before barrier

    #pragma unroll
    for (int kk = 0; kk < 2; ++kk) {
      half8v af[4], bf[4];
      #pragma unroll
      for (int mi = 0; mi < 4; ++mi)
        af[mi] = *(const half8v*)&sA[((kk * 4 + lq) * 128 + wr + mi * 16 + lm) * 8];
      #pragma unroll
      for (int ni = 0; ni < 4; ++ni)
        bf[ni] = *(const half8v*)&sB[((kk * 4 + lq) * 128 + wc + ni * 16 + lm) * 8];
      #pragma unroll
      for (int mi = 0; mi < 4; ++mi)
        #pragma unroll
        for (int ni = 0; ni < 4; ++ni)
          acc[mi][ni] = __builtin_amdgcn_mfma_f32_16x16x32_f16(af[mi], bf[ni], acc[mi][ni], 0, 0, 0);
    }
  }

  float bv[4];
  #pragma unroll
  for (int ni = 0; ni < 4; ++ni) bv[ni] = bias[bn + wc + ni * 16 + lm];

  #pragma unroll
  for (int mi = 0; mi < 4; ++mi)
    #pragma unroll
    for (int ni = 0; ni < 4; ++ni) {
      const int col = bn + wc + ni * 16 + lm;
      if (MODE == 2) {
        const int row0 = bm + wr + mi * 16 + lq * 4;
        half4v pv;
        #pragma unroll
        for (int j = 0; j < 4; ++j) pv[j] = (_Float16)(acc[mi][ni][j] + bv[ni]);
        *(half4v*)(Vt + (size_t)col * 8192 + row0) = pv;
      } else {
        #pragma unroll
        for (int j = 0; j < 4; ++j) {
          const int row = bm + wr + mi * 16 + lq * 4 + j;   // verified C/D mapping
          const float v = acc[mi][ni][j] + bv[ni];
          const size_t idx = (size_t)row * 1024 + col;
          if (MODE == 0) C[idx] = (_Float16)v;
          else           Cf[idx] = (float)X[idx] + fmaxf(v, 0.f);
        }
      }
    }
}

// ============ MFMA attention (fp16) ============
// Grid (hb=128, ks=2). 1024 threads = 16 waves; wave w owns q in [w*32, w*32+32).
// 32 k-tiles of 32. Softmax over q => Z[k] block-local. Per tile: reg-prefetched
// double-buffered K/V staging (2 barriers), S = 1-term fp16 MFMA, Z via shfl +
// cross-wave LDS, P*invZ fp16 to per-wave LDS (no barrier), PV 1-term MFMA.
__global__ __launch_bounds__(1024, 4)
void attn_mfma(const _Float16* __restrict__ Qp,
               const _Float16* __restrict__ K1p, const _Float16* __restrict__ K2p,
               const _Float16* __restrict__ VT1, const _Float16* __restrict__ VT2,
               float* __restrict__ Opart) {
  __shared__ _Float16 sK[2][2048];     // [buf][dchunk 8][k 32][8]   8KB
  __shared__ _Float16 sV[2][2560];     // [buf][d 64][k 32 pad->40] 10KB
  __shared__ _Float16 sP[20480];       // per-wave [q 32][k 32 pad->40] 40KB
  __shared__ float sZ[16][32];         // per-wave column partials   2KB

  const int t    = threadIdx.x;
  const int lane = t & 63;
  const int w    = t >> 6;             // wave 0..15
  const int lm   = lane & 15;
  const int lq   = lane >> 4;
  const int hb   = blockIdx.x;
  const int ks   = blockIdx.y;
  const int h    = hb >> 3;
  const int b    = hb & 7;
  const int qw   = w * 32;
  const _Float16* __restrict__ K  = ks ? K2p : K1p;
  const _Float16* __restrict__ VT = ks ? VT2 : VT1;

  // Q fragments in registers for the whole kernel: [mi 0..1][dh 0..1]
  half8v qf[2][2];
  #pragma unroll
  for (int mi = 0; mi < 2; ++mi)
    #pragma unroll
    for (int dh = 0; dh < 2; ++dh)
      qf[mi][dh] = *(const half8v*)(Qp + (size_t)(b * 512 + qw + mi * 16 + lm) * 1024
                                       + h * 64 + dh * 32 + lq * 8);

  f32x4 o[2][4];
  #pragma unroll
  for (int i = 0; i < 2; ++i)
    #pragma unroll
    for (int j = 0; j < 4; ++j) { f32x4 z = {0.f, 0.f, 0.f, 0.f}; o[i][j] = z; }

  // staging roles: t<256 -> K tile (32k x 64d), t in [256,512) -> V tile (64d x 32k)
  const int ku = t & 255;
  const int sd = ku & 31;              // K: k row
  const int sc = ku >> 5;              // K: d chunk 0..7
  const int vd = ku & 63;              // V: d row
  const int vc = (ku >> 6) & 3;        // V: k chunk 0..3
  _Float16* sPw = sP + w * 1280;       // per-wave 32x40

  half8v rk, rv;
  #define ISSUE_LOADS(K0)                                                                  \
    if (t < 256)      rk = *(const half8v*)(K + (size_t)(b * 1024 + (K0) + sd) * 1024 + h * 64 + sc * 8); \
    else if (t < 512) rv = *(const half8v*)(VT + (size_t)(h * 64 + vd) * 8192 + b * 1024 + (K0) + vc * 8);

  ISSUE_LOADS(0)

  for (int kt = 0; kt < 32; ++kt) {
    const int c = kt & 1;
    if (t < 256)      *(half8v*)&sK[c][(sc * 32 + sd) * 8] = rk;
    else if (t < 512) *(half8v*)&sV[c][vd * 40 + vc * 8] = rv;
    if (kt + 1 < 32) { ISSUE_LOADS((kt + 1) * 32) }
    __syncthreads();   // barB: buf[c] ready

    // ---- S = Q.K^T (single fp16 MFMA per frag)
    f32x4 s[2][2];
    #pragma unroll
    for (int i = 0; i < 2; ++i)
      #pragma unroll
      for (int j = 0; j < 2; ++j) { f32x4 z = {0.f, 0.f, 0.f, 0.f}; s[i][j] = z; }
    #pragma unroll
    for (int dh = 0; dh < 2; ++dh) {
      half8v kb[2];
      #pragma unroll
      for (int fi = 0; fi < 2; ++fi)
        kb[fi] = *(const half8v*)&sK[c][((dh * 4 + lq) * 32 + fi * 16 + lm) * 8];
      #pragma unroll
      for (int mi = 0; mi < 2; ++mi)
        #pragma unroll
        for (int fi = 0; fi < 2; ++fi)
          s[mi][fi] = __builtin_amdgcn_mfma_f32_16x16x32_f16(qf[mi][dh], kb[fi], s[mi][fi], 0, 0, 0);
    }

    // ---- exp + per-wave column partials (k = fi*16+lm)
    float zp[2] = {0.f, 0.f};
    #pragma unroll
    for (int mi = 0; mi < 2; ++mi)
      #pragma unroll
      for (int fi = 0; fi < 2; ++fi)
        #pragma unroll
        for (int j = 0; j < 4; ++j) {
          float p = __expf(s[mi][fi][j] * 0.03125f);   // scores tiny: no max-sub
          s[mi][fi][j] = p;
          zp[fi] += p;
        }
    #pragma unroll
    for (int fi = 0; fi < 2; ++fi) {
      zp[fi] += __shfl_xor(zp[fi], 16);
      zp[fi] += __shfl_xor(zp[fi], 32);
    }
    if (lane < 16) { sZ[w][lm] = zp[0]; sZ[w][16 + lm] = zp[1]; }
    __syncthreads();   // barC: sZ complete

    // ---- invZ: lanes<32 own one k column each, shfl-distribute
    float iz = 0.f;
    if (lane < 32) {
      float z = 0.f;
      #pragma unroll
      for (int wv = 0; wv < 16; ++wv) z += sZ[wv][lane];
      iz = 1.0f / z;
    }
    const float iz0 = __shfl(iz, lm);
    const float iz1 = __shfl(iz, 16 + lm);

    // ---- P*invZ -> per-wave LDS (fp16); intra-wave only, no barrier
    #pragma unroll
    for (int mi = 0; mi < 2; ++mi)
      #pragma unroll
      for (int j = 0; j < 4; ++j) {
        const int q = mi * 16 + lq * 4 + j;
        sPw[q * 40 + lm]      = (_Float16)(s[mi][0][j] * iz0);
        sPw[q * 40 + 16 + lm] = (_Float16)(s[mi][1][j] * iz1);
      }

    // ---- PV: O += P . V  (K-dim 32 = one MFMA)
    half8v pa[2], vb[4];
    #pragma unroll
    for (int mi = 0; mi < 2; ++mi)
      pa[mi] = *(const half8v*)&sPw[(mi * 16 + lm) * 40 + lq * 8];
    #pragma unroll
    for (int ni = 0; ni < 4; ++ni)
      vb[ni] = *(const half8v*)&sV[c][(ni * 16 + lm) * 40 + lq * 8];
    #pragma unroll
    for (int mi = 0; mi < 2; ++mi)
      #pragma unroll
      for (int ni = 0; ni < 4; ++ni)
        o[mi][ni] = __builtin_amdgcn_mfma_f32_16x16x32_f16(pa[mi], vb[ni], o[mi][ni], 0, 0, 0);
  }
  #undef ISSUE_LOADS

  // ---- epilogue: Opart[ks][hb][q][d]
  float* dst = Opart + (size_t)(ks * 128 + hb) * 512 * 64;
  #pragma unroll
  for (int mi = 0; mi < 2; ++mi)
    #pragma unroll
    for (int ni = 0; ni < 4; ++ni)
      #pragma unroll
      for (int j = 0; j < 4; ++j) {
        const int q = qw + mi * 16 + lq * 4 + j;
        const int d = ni * 16 + lm;
        dst[(size_t)q * 64 + d] = o[mi][ni][j];
      }
}

// ============ LayerNorm ============
// MODE 0: v = Qp(fp16) + Op[0] + Op[1] (merge-heads+residual); out fp16
// MODE 1: v = fin[row]; out fp32
template<int MODE>
__global__ __launch_bounds__(256)
void ln_kernel(const float* __restrict__ fin, const _Float16* __restrict__ Qp,
               const float* __restrict__ g, const float* __restrict__ beta,
               _Float16* __restrict__ oh, float* __restrict__ of) {
  const int row = blockIdx.x;          // b*512 + n
  const int t = threadIdx.x;
  const int c = t * 4;
  float4 v;
  if (MODE == 0) {
    const int b  = row >> 9;
    const int n  = row & 511;
    const int hh = c >> 6;
    const int d  = c & 63;
    const int hb = hh * 8 + b;
    half4v qv = *(const half4v*)(Qp + (size_t)row * 1024 + c);
    float4 p0 = *(const float4*)&fin[((size_t)hb         * 512 + n) * 64 + d];
    float4 p1 = *(const float4*)&fin[((size_t)(128 + hb) * 512 + n) * 64 + d];
    v = make_float4((float)qv[0] + p0.x + p1.x, (float)qv[1] + p0.y + p1.y,
                    (float)qv[2] + p0.z + p1.z, (float)qv[3] + p0.w + p1.w);
  } else {
    v = *(const float4*)&fin[(size_t)row * 1024 + c];
  }
  float s  = v.x + v.y + v.z + v.w;
  float s2 = v.x * v.x + v.y * v.y + v.z * v.z + v.w * v.w;
  #pragma unroll
  for (int m = 1; m < 64; m <<= 1) { s += __shfl_xor(s, m); s2 += __shfl_xor(s2, m); }
  __shared__ float aS[4], aS2[4];
  const int wid = t >> 6;
  if ((t & 63) == 0) { aS[wid] = s; aS2[wid] = s2; }
  __syncthreads();
  s  = aS[0] + aS[1] + aS[2] + aS[3];
  s2 = aS2[0] + aS2[1] + aS2[2] + aS2[3];
  const float mean = s * (1.f / 1024.f);
  const float var  = s2 * (1.f / 1024.f) - mean * mean;
  const float rstd = rsqrtf(var + 1e-5f);
  float4 gg = *(const float4*)&g[c];
  float4 bb = *(const float4*)&beta[c];
  float4 ov = make_float4((v.x - mean) * rstd * gg.x + bb.x,
                          (v.y - mean) * rstd * gg.y + bb.y,
                          (v.z - mean) * rstd * gg.z + bb.z,
                          (v.w - mean) * rstd * gg.w + bb.w);
  const size_t oi = (size_t)row * 1024 + c;
  if (MODE == 0) {
    half4v hv;
    hv[0] = (_Float16)ov.x; hv[1] = (_Float16)ov.y;
    hv[2] = (_Float16)ov.z; hv[3] = (_Float16)ov.w;
    *(half4v*)(oh + oi) = hv;
  } else {
    *(float4*)(of + oi) = ov;
  }
}

extern "C" void kernel_launch(void* const* d_in, const int* in_sizes, int n_in,
                              void* d_out, int out_size, void* d_ws, size_t ws_size,
                              hipStream_t stream) {
  (void)in_sizes; (void)n_in; (void)out_size; (void)ws_size;
  const float* Q   = (const float*)d_in[0];
  const float* K1  = (const float*)d_in[1];
  const float* K2  = (const float*)d_in[2];
  const float* Wq  = (const float*)d_in[3];
  const float* bq  = (const float*)d_in[4];
  const float* Wk1 = (const float*)d_in[5];
  const float* bk1 = (const float*)d_in[6];
  const float* Wk2 = (const float*)d_in[7];
  const float* bk2 = (const float*)d_in[8];
  const float* Wv1 = (const float*)d_in[9];
  const float* bv1 = (const float*)d_in[10];
  const float* Wv2 = (const float*)d_in[11];
  const float* bv2 = (const float*)d_in[12];
  const float* Wo  = (const float*)d_in[13];
  const float* bo  = (const float*)d_in[14];
  const float* g0  = (const float*)d_in[15];
  const float* be0 = (const float*)d_in[16];
  const float* g1  = (const float*)d_in[17];
  const float* be1 = (const float*)d_in[18];

  // ---- workspace layout (byte offsets; total 156 MB) ----
  // Qc 0-8 | K1c 8-24 | K2c 24-40 | Wt x6 40-52 | Qp 52-60 | K1p 60-76 |
  // K2p 76-92 | VT1 92-108 | VT2 108-124 | Op 124-156 (fp32)
  // overlays: x0 = 0-8 (Qc dead), tb fp32 = 8-24 (K1c dead)
  char* WS = (char*)d_ws;
  const size_t MB = 1024 * 1024;
  auto S = [&](size_t off) { return (_Float16*)(WS + off); };
  _Float16 *Qc = S(0), *K1c = S(8 * MB), *K2c = S(24 * MB);
  _Float16 *Wt[6];
  for (int i = 0; i < 6; ++i) Wt[i] = S(40 * MB + i * 2 * MB);
  _Float16 *Qp  = S(52 * MB);
  _Float16 *K1p = S(60 * MB), *K2p = S(76 * MB);
  _Float16 *VT1 = S(92 * MB), *VT2 = S(108 * MB);
  float* Op = (float*)(WS + 124 * MB);
  _Float16 *x0 = S(0);                    // overlays Qc
  float* tb = (float*)(WS + 8 * MB);      // overlays K1c

  WPArgs wa;
  const float* wsrc[6] = {Wq, Wk1, Wk2, Wv1, Wv2, Wo};
  for (int i = 0; i < 6; ++i) { wa.w[i].src = wsrc[i]; wa.w[i].dst = Wt[i]; }

  wprep_kernel<<<dim3(32, 32, 6), 256, 0, stream>>>(wa);
  aconv_kernel<<<dim3(4096), 256, 0, stream>>>(Q,  Qc,  1048576);
  aconv_kernel<<<dim3(8192), 256, 0, stream>>>(K1, K1c, 2097152);
  aconv_kernel<<<dim3(8192), 256, 0, stream>>>(K2, K2c, 2097152);

  gemm_fp16<0><<<dim3(8, 32), 256, 0, stream>>>(Qc,  Wt[0], bq,  nullptr, Qp,  nullptr, nullptr);
  gemm_fp16<0><<<dim3(8, 64), 256, 0, stream>>>(K1c, Wt[1], bk1, nullptr, K1p, nullptr, nullptr);
  gemm_fp16<0><<<dim3(8, 64), 256, 0, stream>>>(K2c, Wt[2], bk2, nullptr, K2p, nullptr, nullptr);
  gemm_fp16<2><<<dim3(8, 64), 256, 0, stream>>>(K1p, Wt[3], bv1, nullptr, nullptr, nullptr, VT1);
  gemm_fp16<2><<<dim3(8, 64), 256, 0, stream>>>(K2p, Wt[4], bv2, nullptr, nullptr, nullptr, VT2);

  attn_mfma<<<dim3(128, 2), dim3(1024), 0, stream>>>(Qp, K1p, K2p, VT1, VT2, Op);

  ln_kernel<0><<<dim3(4096), 256, 0, stream>>>(Op, Qp, g0, be0, x0, nullptr);
  gemm_fp16<1><<<dim3(8, 32), 256, 0, stream>>>(x0, Wt[5], bo, x0, nullptr, tb, nullptr);
  ln_kernel<1><<<dim3(4096), 256, 0, stream>>>(tb, nullptr, g1, be1, nullptr, (float*)d_out);
}

// Round 7
// 488.721 us; speedup vs baseline: 2.5980x; 1.0078x over previous
//
#include <hip/hip_runtime.h>
#include <math.h>

typedef __attribute__((ext_vector_type(8))) _Float16 half8v;   // 8 fp16 = 4 VGPR
typedef __attribute__((ext_vector_type(4))) _Float16 half4v;
typedef __attribute__((ext_vector_type(4))) float f32x4;

__device__ __forceinline__ void gload16(const void* g, void* l) {
  // global -> LDS direct DMA, 16 B per lane. LDS dest = wave-uniform base + lane*16.
  __builtin_amdgcn_global_load_lds(
      (const __attribute__((address_space(1))) void*)g,
      (__attribute__((address_space(3))) void*)l, 16, 0, 0);
}

// ============ weight prep: W[k][n] fp32 -> Wt[n][k] fp16 (transpose+cast) ============
struct WP { const float* src; _Float16* dst; };
struct WPArgs { WP w[6]; };

__global__ __launch_bounds__(256)
void wprep_kernel(WPArgs args) {
  __shared__ float tile[32][33];
  const WP wp = args.w[blockIdx.z];
  const int t  = threadIdx.x;
  const int r  = t >> 3;            // 0..31
  const int c  = (t & 7) * 4;       // 0..28
  const int n0 = blockIdx.x * 32;
  const int k0 = blockIdx.y * 32;
  float4 v = *(const float4*)(wp.src + (size_t)(k0 + r) * 1024 + n0 + c);
  tile[r][c] = v.x; tile[r][c + 1] = v.y; tile[r][c + 2] = v.z; tile[r][c + 3] = v.w;
  __syncthreads();
  half4v h;
  #pragma unroll
  for (int i = 0; i < 4; ++i) h[i] = (_Float16)tile[c + i][r];
  *(half4v*)(wp.dst + (size_t)(n0 + r) * 1024 + k0 + c) = h;
}

// ============ activation cast: fp32 -> fp16 ============
__global__ __launch_bounds__(256)
void aconv_kernel(const float* __restrict__ in, _Float16* __restrict__ out, int n4) {
  int i = blockIdx.x * 256 + threadIdx.x;
  if (i >= n4) return;
  float4 v = ((const float4*)in)[i];
  half4v o;
  o[0] = (_Float16)v.x; o[1] = (_Float16)v.y; o[2] = (_Float16)v.z; o[3] = (_Float16)v.w;
  ((half4v*)out)[i] = o;
}

// ============ fp16 MFMA GEMM: C[M,1024] = A @ Wt^T + bias ============
// 1D grid (8*NM blocks), XCD-chunked swizzle: xcd=bid&7 owns m-rows
// [xcd*NM/8, (xcd+1)*NM/8), n fastest -> A-panel read once per XCD,
// per-XCD L2 working set = A-chunk 2MB + B 2MB.
// 128x128 tile, BK=64, 4 waves, global_load_lds staging.
// MODE 0: C fp16 (LDS-staged coalesced epilogue).
// MODE 1: Cf = X + relu(C+bias) fp32 (direct stores).
// MODE 2: C^T fp16 -> Vt[n][8192] (LDS-staged coalesced epilogue).
template<int MODE>
__global__ __launch_bounds__(256)
void gemm_fp16(const _Float16* __restrict__ A, const _Float16* __restrict__ B,
               const float* __restrict__ bias, const _Float16* __restrict__ X,
               _Float16* __restrict__ C, float* __restrict__ Cf,
               _Float16* __restrict__ Vt, int NM) {
  __shared__ _Float16 smem[16384];            // 32KB: sA | sB ; reused as sT epilogue
  _Float16* const sA = smem;
  _Float16* const sB = smem + 8192;
  const int t    = threadIdx.x;
  const int bid  = blockIdx.x;
  const int xcd  = bid & 7;
  const int li   = bid >> 3;                  // 0..NM-1
  const int m    = xcd * (NM >> 3) + (li >> 3);
  const int n    = li & 7;
  const int bm   = m * 128;
  const int bn   = n * 128;
  const int lane = t & 63;
  const int w    = t >> 6;
  const int wr   = (w >> 1) * 64;
  const int wc   = (w & 1) * 64;
  const int lm   = lane & 15;
  const int lq   = lane >> 4;

  f32x4 acc[4][4];
  #pragma unroll
  for (int i = 0; i < 4; ++i)
    #pragma unroll
    for (int j = 0; j < 4; ++j) { f32x4 z = {0.f, 0.f, 0.f, 0.f}; acc[i][j] = z; }

  for (int k0 = 0; k0 < 1024; k0 += 64) {
    __syncthreads();                     // frag reads of previous iter complete
    #pragma unroll
    for (int i = 0; i < 4; ++i) {
      const int T    = w * 4 + i;        // 0..15: kq = T>>1, row-half = T&1
      const int kq   = T >> 1;
      const int row  = (T & 1) * 64 + lane;
      gload16(A + (size_t)(bm + row) * 1024 + k0 + kq * 8, &sA[(T * 64 + lane) * 8]);
      gload16(B + (size_t)(bn + row) * 1024 + k0 + kq * 8, &sB[(T * 64 + lane) * 8]);
    }
    __syncthreads();                     // vmcnt drained before barrier

    #pragma unroll
    for (int kk = 0; kk < 2; ++kk) {
      half8v af[4], bf[4];
      #pragma unroll
      for (int mi = 0; mi < 4; ++mi)
        af[mi] = *(const half8v*)&sA[((kk * 4 + lq) * 128 + wr + mi * 16 + lm) * 8];
      #pragma unroll
      for (int ni = 0; ni < 4; ++ni)
        bf[ni] = *(const half8v*)&sB[((kk * 4 + lq) * 128 + wc + ni * 16 + lm) * 8];
      #pragma unroll
      for (int mi = 0; mi < 4; ++mi)
        #pragma unroll
        for (int ni = 0; ni < 4; ++ni)
          acc[mi][ni] = __builtin_amdgcn_mfma_f32_16x16x32_f16(af[mi], bf[ni], acc[mi][ni], 0, 0, 0);
    }
  }

  float bv[4];
  #pragma unroll
  for (int ni = 0; ni < 4; ++ni) bv[ni] = bias[bn + wc + ni * 16 + lm];

  if (MODE == 1) {
    #pragma unroll
    for (int mi = 0; mi < 4; ++mi)
      #pragma unroll
      for (int ni = 0; ni < 4; ++ni) {
        const int col = bn + wc + ni * 16 + lm;
        #pragma unroll
        for (int j = 0; j < 4; ++j) {
          const int row = bm + wr + mi * 16 + lq * 4 + j;
          const size_t idx = (size_t)row * 1024 + col;
          Cf[idx] = (float)X[idx] + fmaxf(acc[mi][ni][j] + bv[ni], 0.f);
        }
      }
    return;
  }

  // MODE 0 / 2: stage tile in LDS (fp16), then coalesced 16B-per-lane writes.
  __syncthreads();                       // all waves done reading sA/sB
  #pragma unroll
  for (int mi = 0; mi < 4; ++mi)
    #pragma unroll
    for (int ni = 0; ni < 4; ++ni) {
      const int cc = wc + ni * 16 + lm;
      #pragma unroll
      for (int j = 0; j < 4; ++j) {
        const int rr = wr + mi * 16 + lq * 4 + j;
        const _Float16 v = (_Float16)(acc[mi][ni][j] + bv[ni]);
        if (MODE == 0) smem[rr * 128 + cc] = v;    // sT[m][n]
        else           smem[cc * 128 + rr] = v;    // sT[n][m] (transposed out)
      }
    }
  __syncthreads();
  const int r16 = t >> 4;                // 0..15
  const int c8  = (t & 15) * 8;          // half-offset 0..120
  #pragma unroll
  for (int p = 0; p < 8; ++p) {
    const int row = p * 16 + r16;
    half8v vv = *(const half8v*)&smem[row * 128 + c8];
    if (MODE == 0) *(half8v*)(C + (size_t)(bm + row) * 1024 + bn + c8) = vv;
    else           *(half8v*)(Vt + (size_t)(bn + row) * 8192 + bm + c8) = vv;
  }
}

// ============ MFMA attention (fp16) ============
// Grid (hb=128, ks=2). 1024 threads = 16 waves; wave w owns q in [w*32, w*32+32).
// 32 k-tiles of 32. Softmax over q => Z[k] block-local. Per tile: reg-prefetched
// double-buffered K/V staging (2 barriers), S = fp16 MFMA, Z via shfl +
// cross-wave LDS, P*invZ fp16 to per-wave LDS (no barrier), PV MFMA.
__global__ __launch_bounds__(1024, 4)
void attn_mfma(const _Float16* __restrict__ Qp,
               const _Float16* __restrict__ K1p, const _Float16* __restrict__ K2p,
               const _Float16* __restrict__ VT1, const _Float16* __restrict__ VT2,
               float* __restrict__ Opart) {
  __shared__ _Float16 sK[2][2048];     // [buf][dchunk 8][k 32][8]   8KB
  __shared__ _Float16 sV[2][2560];     // [buf][d 64][k 32 pad->40] 10KB
  __shared__ _Float16 sP[20480];       // per-wave [q 32][k 32 pad->40] 40KB
  __shared__ float sZ[16][32];         // per-wave column partials   2KB

  const int t    = threadIdx.x;
  const int lane = t & 63;
  const int w    = t >> 6;             // wave 0..15
  const int lm   = lane & 15;
  const int lq   = lane >> 4;
  const int hb   = blockIdx.x;
  const int ks   = blockIdx.y;
  const int h    = hb >> 3;
  const int b    = hb & 7;
  const int qw   = w * 32;
  const _Float16* __restrict__ K  = ks ? K2p : K1p;
  const _Float16* __restrict__ VT = ks ? VT2 : VT1;

  half8v qf[2][2];
  #pragma unroll
  for (int mi = 0; mi < 2; ++mi)
    #pragma unroll
    for (int dh = 0; dh < 2; ++dh)
      qf[mi][dh] = *(const half8v*)(Qp + (size_t)(b * 512 + qw + mi * 16 + lm) * 1024
                                       + h * 64 + dh * 32 + lq * 8);

  f32x4 o[2][4];
  #pragma unroll
  for (int i = 0; i < 2; ++i)
    #pragma unroll
    for (int j = 0; j < 4; ++j) { f32x4 z = {0.f, 0.f, 0.f, 0.f}; o[i][j] = z; }

  const int ku = t & 255;
  const int sd = ku & 31;              // K: k row
  const int sc = ku >> 5;              // K: d chunk 0..7
  const int vd = ku & 63;              // V: d row
  const int vc = (ku >> 6) & 3;        // V: k chunk 0..3
  _Float16* sPw = sP + w * 1280;       // per-wave 32x40

  half8v rk, rv;
  #define ISSUE_LOADS(K0)                                                                  \
    if (t < 256)      rk = *(const half8v*)(K + (size_t)(b * 1024 + (K0) + sd) * 1024 + h * 64 + sc * 8); \
    else if (t < 512) rv = *(const half8v*)(VT + (size_t)(h * 64 + vd) * 8192 + b * 1024 + (K0) + vc * 8);

  ISSUE_LOADS(0)

  for (int kt = 0; kt < 32; ++kt) {
    const int c = kt & 1;
    if (t < 256)      *(half8v*)&sK[c][(sc * 32 + sd) * 8] = rk;
    else if (t < 512) *(half8v*)&sV[c][vd * 40 + vc * 8] = rv;
    if (kt + 1 < 32) { ISSUE_LOADS((kt + 1) * 32) }
    __syncthreads();   // barB: buf[c] ready

    // ---- S = Q.K^T
    f32x4 s[2][2];
    #pragma unroll
    for (int i = 0; i < 2; ++i)
      #pragma unroll
      for (int j = 0; j < 2; ++j) { f32x4 z = {0.f, 0.f, 0.f, 0.f}; s[i][j] = z; }
    __builtin_amdgcn_s_setprio(1);
    #pragma unroll
    for (int dh = 0; dh < 2; ++dh) {
      half8v kb[2];
      #pragma unroll
      for (int fi = 0; fi < 2; ++fi)
        kb[fi] = *(const half8v*)&sK[c][((dh * 4 + lq) * 32 + fi * 16 + lm) * 8];
      #pragma unroll
      for (int mi = 0; mi < 2; ++mi)
        #pragma unroll
        for (int fi = 0; fi < 2; ++fi)
          s[mi][fi] = __builtin_amdgcn_mfma_f32_16x16x32_f16(qf[mi][dh], kb[fi], s[mi][fi], 0, 0, 0);
    }
    __builtin_amdgcn_s_setprio(0);

    // ---- exp + per-wave column partials (k = fi*16+lm)
    float zp[2] = {0.f, 0.f};
    #pragma unroll
    for (int mi = 0; mi < 2; ++mi)
      #pragma unroll
      for (int fi = 0; fi < 2; ++fi)
        #pragma unroll
        for (int j = 0; j < 4; ++j) {
          float p = __expf(s[mi][fi][j] * 0.03125f);   // scores tiny: no max-sub
          s[mi][fi][j] = p;
          zp[fi] += p;
        }
    #pragma unroll
    for (int fi = 0; fi < 2; ++fi) {
      zp[fi] += __shfl_xor(zp[fi], 16);
      zp[fi] += __shfl_xor(zp[fi], 32);
    }
    if (lane < 16) { sZ[w][lm] = zp[0]; sZ[w][16 + lm] = zp[1]; }
    __syncthreads();   // barC: sZ complete

    // ---- invZ: lanes<32 own one k column each, shfl-distribute
    float iz = 0.f;
    if (lane < 32) {
      float z = 0.f;
      #pragma unroll
      for (int wv = 0; wv < 16; ++wv) z += sZ[wv][lane];
      iz = 1.0f / z;
    }
    const float iz0 = __shfl(iz, lm);
    const float iz1 = __shfl(iz, 16 + lm);

    // ---- P*invZ -> per-wave LDS (fp16); intra-wave only, no barrier
    #pragma unroll
    for (int mi = 0; mi < 2; ++mi)
      #pragma unroll
      for (int j = 0; j < 4; ++j) {
        const int q = mi * 16 + lq * 4 + j;
        sPw[q * 40 + lm]      = (_Float16)(s[mi][0][j] * iz0);
        sPw[q * 40 + 16 + lm] = (_Float16)(s[mi][1][j] * iz1);
      }

    // ---- PV: O += P . V
    half8v pa[2], vb[4];
    #pragma unroll
    for (int mi = 0; mi < 2; ++mi)
      pa[mi] = *(const half8v*)&sPw[(mi * 16 + lm) * 40 + lq * 8];
    #pragma unroll
    for (int ni = 0; ni < 4; ++ni)
      vb[ni] = *(const half8v*)&sV[c][(ni * 16 + lm) * 40 + lq * 8];
    __builtin_amdgcn_s_setprio(1);
    #pragma unroll
    for (int mi = 0; mi < 2; ++mi)
      #pragma unroll
      for (int ni = 0; ni < 4; ++ni)
        o[mi][ni] = __builtin_amdgcn_mfma_f32_16x16x32_f16(pa[mi], vb[ni], o[mi][ni], 0, 0, 0);
    __builtin_amdgcn_s_setprio(0);
  }
  #undef ISSUE_LOADS

  // ---- epilogue: Opart[ks][hb][q][d]
  float* dst = Opart + (size_t)(ks * 128 + hb) * 512 * 64;
  #pragma unroll
  for (int mi = 0; mi < 2; ++mi)
    #pragma unroll
    for (int ni = 0; ni < 4; ++ni)
      #pragma unroll
      for (int j = 0; j < 4; ++j) {
        const int q = qw + mi * 16 + lq * 4 + j;
        const int d = ni * 16 + lm;
        dst[(size_t)q * 64 + d] = o[mi][ni][j];
      }
}

// ============ LayerNorm ============
// MODE 0: v = Qp(fp16) + Op[0] + Op[1] (merge-heads+residual); out fp16
// MODE 1: v = fin[row]; out fp32
template<int MODE>
__global__ __launch_bounds__(256)
void ln_kernel(const float* __restrict__ fin, const _Float16* __restrict__ Qp,
               const float* __restrict__ g, const float* __restrict__ beta,
               _Float16* __restrict__ oh, float* __restrict__ of) {
  const int row = blockIdx.x;          // b*512 + n
  const int t = threadIdx.x;
  const int c = t * 4;
  float4 v;
  if (MODE == 0) {
    const int b  = row >> 9;
    const int n  = row & 511;
    const int hh = c >> 6;
    const int d  = c & 63;
    const int hb = hh * 8 + b;
    half4v qv = *(const half4v*)(Qp + (size_t)row * 1024 + c);
    float4 p0 = *(const float4*)&fin[((size_t)hb         * 512 + n) * 64 + d];
    float4 p1 = *(const float4*)&fin[((size_t)(128 + hb) * 512 + n) * 64 + d];
    v = make_float4((float)qv[0] + p0.x + p1.x, (float)qv[1] + p0.y + p1.y,
                    (float)qv[2] + p0.z + p1.z, (float)qv[3] + p0.w + p1.w);
  } else {
    v = *(const float4*)&fin[(size_t)row * 1024 + c];
  }
  float s  = v.x + v.y + v.z + v.w;
  float s2 = v.x * v.x + v.y * v.y + v.z * v.z + v.w * v.w;
  #pragma unroll
  for (int m = 1; m < 64; m <<= 1) { s += __shfl_xor(s, m); s2 += __shfl_xor(s2, m); }
  __shared__ float aS[4], aS2[4];
  const int wid = t >> 6;
  if ((t & 63) == 0) { aS[wid] = s; aS2[wid] = s2; }
  __syncthreads();
  s  = aS[0] + aS[1] + aS[2] + aS[3];
  s2 = aS2[0] + aS2[1] + aS2[2] + aS2[3];
  const float mean = s * (1.f / 1024.f);
  const float var  = s2 * (1.f / 1024.f) - mean * mean;
  const float rstd = rsqrtf(var + 1e-5f);
  float4 gg = *(const float4*)&g[c];
  float4 bb = *(const float4*)&beta[c];
  float4 ov = make_float4((v.x - mean) * rstd * gg.x + bb.x,
                          (v.y - mean) * rstd * gg.y + bb.y,
                          (v.z - mean) * rstd * gg.z + bb.z,
                          (v.w - mean) * rstd * gg.w + bb.w);
  const size_t oi = (size_t)row * 1024 + c;
  if (MODE == 0) {
    half4v hv;
    hv[0] = (_Float16)ov.x; hv[1] = (_Float16)ov.y;
    hv[2] = (_Float16)ov.z; hv[3] = (_Float16)ov.w;
    *(half4v*)(oh + oi) = hv;
  } else {
    *(float4*)(of + oi) = ov;
  }
}

extern "C" void kernel_launch(void* const* d_in, const int* in_sizes, int n_in,
                              void* d_out, int out_size, void* d_ws, size_t ws_size,
                              hipStream_t stream) {
  (void)in_sizes; (void)n_in; (void)out_size; (void)ws_size;
  const float* Q   = (const float*)d_in[0];
  const float* K1  = (const float*)d_in[1];
  const float* K2  = (const float*)d_in[2];
  const float* Wq  = (const float*)d_in[3];
  const float* bq  = (const float*)d_in[4];
  const float* Wk1 = (const float*)d_in[5];
  const float* bk1 = (const float*)d_in[6];
  const float* Wk2 = (const float*)d_in[7];
  const float* bk2 = (const float*)d_in[8];
  const float* Wv1 = (const float*)d_in[9];
  const float* bv1 = (const float*)d_in[10];
  const float* Wv2 = (const float*)d_in[11];
  const float* bv2 = (const float*)d_in[12];
  const float* Wo  = (const float*)d_in[13];
  const float* bo  = (const float*)d_in[14];
  const float* g0  = (const float*)d_in[15];
  const float* be0 = (const float*)d_in[16];
  const float* g1  = (const float*)d_in[17];
  const float* be1 = (const float*)d_in[18];

  // ---- workspace layout (byte offsets; total 156 MB) ----
  // Qc 0-8 | K1c 8-24 | K2c 24-40 | Wt x6 40-52 | Qp 52-60 | K1p 60-76 |
  // K2p 76-92 | VT1 92-108 | VT2 108-124 | Op 124-156 (fp32)
  // overlays: x0 = 0-8 (Qc dead), tb fp32 = 8-24 (K1c dead)
  char* WS = (char*)d_ws;
  const size_t MB = 1024 * 1024;
  auto S = [&](size_t off) { return (_Float16*)(WS + off); };
  _Float16 *Qc = S(0), *K1c = S(8 * MB), *K2c = S(24 * MB);
  _Float16 *Wt[6];
  for (int i = 0; i < 6; ++i) Wt[i] = S(40 * MB + i * 2 * MB);
  _Float16 *Qp  = S(52 * MB);
  _Float16 *K1p = S(60 * MB), *K2p = S(76 * MB);
  _Float16 *VT1 = S(92 * MB), *VT2 = S(108 * MB);
  float* Op = (float*)(WS + 124 * MB);
  _Float16 *x0 = S(0);                    // overlays Qc
  float* tb = (float*)(WS + 8 * MB);      // overlays K1c

  WPArgs wa;
  const float* wsrc[6] = {Wq, Wk1, Wk2, Wv1, Wv2, Wo};
  for (int i = 0; i < 6; ++i) { wa.w[i].src = wsrc[i]; wa.w[i].dst = Wt[i]; }

  wprep_kernel<<<dim3(32, 32, 6), 256, 0, stream>>>(wa);
  aconv_kernel<<<dim3(4096), 256, 0, stream>>>(Q,  Qc,  1048576);
  aconv_kernel<<<dim3(8192), 256, 0, stream>>>(K1, K1c, 2097152);
  aconv_kernel<<<dim3(8192), 256, 0, stream>>>(K2, K2c, 2097152);

  gemm_fp16<0><<<dim3(256), 256, 0, stream>>>(Qc,  Wt[0], bq,  nullptr, Qp,  nullptr, nullptr, 32);
  gemm_fp16<0><<<dim3(512), 256, 0, stream>>>(K1c, Wt[1], bk1, nullptr, K1p, nullptr, nullptr, 64);
  gemm_fp16<0><<<dim3(512), 256, 0, stream>>>(K2c, Wt[2], bk2, nullptr, K2p, nullptr, nullptr, 64);
  gemm_fp16<2><<<dim3(512), 256, 0, stream>>>(K1p, Wt[3], bv1, nullptr, nullptr, nullptr, VT1, 64);
  gemm_fp16<2><<<dim3(512), 256, 0, stream>>>(K2p, Wt[4], bv2, nullptr, nullptr, nullptr, VT2, 64);

  attn_mfma<<<dim3(128, 2), dim3(1024), 0, stream>>>(Qp, K1p, K2p, VT1, VT2, Op);

  ln_kernel<0><<<dim3(4096), 256, 0, stream>>>(Op, Qp, g0, be0, x0, nullptr);
  gemm_fp16<1><<<dim3(256), 256, 0, stream>>>(x0, Wt[5], bo, x0, nullptr, tb, nullptr, 32);
  ln_kernel<1><<<dim3(4096), 256, 0, stream>>>(tb, nullptr, g1, be1, nullptr, (float*)d_out);
}